// Round 16
// baseline (297.359 us; speedup 1.0000x reference)
//
#include <hip/hip_runtime.h>
#include <math.h>

typedef unsigned short u16;
typedef unsigned int   u32;
typedef unsigned long long u64;

#define NATOMS 8192
#define GRAPHS 64
#define APG    128
#define KNN    32
#define NGAUSS 50
#define HID    128
#define LAYERS 6
#define NTAB   4096
#define SA     136   // u16 stride, 272B rows (16B-aligned)
#define SH     132   // f32 stride, 528B rows (16B-aligned)

typedef __attribute__((ext_vector_type(8))) short bf16x8;
typedef __attribute__((ext_vector_type(4))) float f32x4;

__device__ __forceinline__ float bf2f(u16 v) {
    return __uint_as_float(((u32)v) << 16);
}
__device__ __forceinline__ u16 f2bf(float f) {
    u32 u = __float_as_uint(f);
    u32 lsb = (u >> 16) & 1u;
    u += 0x7fffu + lsb;
    return (u16)(u >> 16);
}
__device__ __forceinline__ u32 pkbf(float lo, float hi) {
#if __has_builtin(__builtin_amdgcn_cvt_pk_bf16_f32)
    auto r = __builtin_amdgcn_cvt_pk_bf16_f32(lo, hi);
    u32 u; __builtin_memcpy(&u, &r, 4); return u;
#else
    return (u32)f2bf(lo) | ((u32)f2bf(hi) << 16);
#endif
}
__device__ __forceinline__ float silu_f(float x) {
    return x * __builtin_amdgcn_rcpf(1.0f + __expf(-x));
}
__device__ __forceinline__ bf16x8 ldfrag(const u16* p) {
    return *(const bf16x8*)__builtin_assume_aligned(p, 16);
}
__device__ __forceinline__ u64 shfl_xor_u64(u64 v, int mask) {
    u32 lo = (u32)v, hi = (u32)(v >> 32);
    lo = (u32)__shfl_xor((int)lo, mask, 64);
    hi = (u32)__shfl_xor((int)hi, mask, 64);
    return ((u64)hi << 32) | lo;
}
union U8 { bf16x8 v; u32 w[4]; };

// ---------------------------------------------------------------------------
// K0: dtype probe + zero rev_cnt/gsum (folds 2 memset dispatches).
// ---------------------------------------------------------------------------
__global__ void probe_kernel(const u16* __restrict__ raw, int* __restrict__ flag,
                             int* __restrict__ rev_cnt, float* __restrict__ gsum) {
    __shared__ int s;
    int t = threadIdx.x;
    if (t == 0) s = 0;
    __syncthreads();
    float x = bf2f(raw[2 * t]);
    if (!(fabsf(x) < 1000.0f)) atomicOr(&s, 1);
    for (int i = t; i < NATOMS; i += 256) rev_cnt[i] = 0;
    if (t < GRAPHS) gsum[t] = 0.0f;
    __syncthreads();
    if (t == 0) *flag = s;
}

// ---------------------------------------------------------------------------
// K0b: ingest fp32-canonical copies (small arrays only).
// ---------------------------------------------------------------------------
#define NARR 10
struct IngestDesc {
    const void* src[NARR];
    void*       dst[NARR];
    int         n[NARR];
};

__global__ void ingest_kernel(IngestDesc d, const int* __restrict__ flag, int total) {
    int gid = blockIdx.x * blockDim.x + threadIdx.x;
    if (gid >= total) return;
    int a = 0, off = gid;
    while (off >= d.n[a]) { off -= d.n[a]; ++a; }
    bool f32in = (*flag != 0);
    float v = f32in ? ((const float*)d.src[a])[off]
                    : bf2f(((const u16*)d.src[a])[off]);
    ((float*)d.dst[a])[off] = v;
}

// ---------------------------------------------------------------------------
// K0c: weight prep — transpose l1w/l2w/mw2 to [n][k] bf16; mw1 -> [n][64]
// (k>=50 zero-padded). All are MFMA B-operands.
// ---------------------------------------------------------------------------
__global__ void prep_weights(const void* __restrict__ l1w, const void* __restrict__ l2w,
                             const void* __restrict__ mw2, const void* __restrict__ mw1,
                             u16* __restrict__ l1wt, u16* __restrict__ l2wt,
                             u16* __restrict__ mw2t, u16* __restrict__ mw1t,
                             const int* __restrict__ flag) {
    int gid = blockIdx.x * blockDim.x + threadIdx.x;
    bool f32in = (*flag != 0);
    if (gid < 3 * 98304) {
        int seg = gid / 98304;
        int t = gid % 98304;
        int l = t >> 14;
        int n = (t >> 7) & 127;
        int k = t & 127;
        const void* src = (seg == 0) ? l1w : ((seg == 1) ? l2w : mw2);
        u16* dst = (seg == 0) ? l1wt : ((seg == 1) ? l2wt : mw2t);
        int si = l * 16384 + k * 128 + n;
        float v = f32in ? ((const float*)src)[si] : bf2f(((const u16*)src)[si]);
        dst[t] = f2bf(v);
    } else {
        int t = gid - 3 * 98304;
        if (t < 49152) {
            int l = t >> 13;
            int n = (t >> 6) & 127;
            int k = t & 63;
            float v = 0.0f;
            if (k < 50) {
                int si = l * 6400 + k * 128 + n;
                v = f32in ? ((const float*)mw1)[si] : bf2f(((const u16*)mw1)[si]);
            }
            mw1t[t] = f2bf(v);
        }
    }
}

// ---------------------------------------------------------------------------
// K1: graph build + edge prep. One WAVE per center; full bitonic sort of 128
// (d2,j) u64 keys (verified R10-R15). Valid edges -> receiver lists with
// (src atom, NEAREST table row index).
// ---------------------------------------------------------------------------
__launch_bounds__(256)
__global__ void build_graph_kernel(const float* __restrict__ pos,
                                   int* __restrict__ rev_cnt,
                                   int2* __restrict__ rev_si) {
    int wv = threadIdx.x >> 6, lane = threadIdx.x & 63;
    int t = blockIdx.x * 4 + wv;
    int tl = t & 127;
    int base = t & ~127;
    float cx = pos[t * 3 + 0];
    float cy = pos[t * 3 + 1];
    float cz = pos[t * 3 + 2];
    u64 key[2];
#pragma unroll
    for (int c = 0; c < 2; ++c) {
        int j = lane + c * 64;
        float jx = pos[(base + j) * 3 + 0];
        float jy = pos[(base + j) * 3 + 1];
        float jz = pos[(base + j) * 3 + 2];
        float dx = __fsub_rn(cx, jx);
        float dy = __fsub_rn(cy, jy);
        float dz = __fsub_rn(cz, jz);
        float d2 = __fadd_rn(__fadd_rn(__fmul_rn(dx, dx), __fmul_rn(dy, dy)),
                             __fmul_rn(dz, dz));
        bool valid = (j != tl) && (d2 < 100.0f);
        key[c] = valid ? ((((u64)__float_as_uint(d2)) << 32) | (u32)j) : ~0ULL;
    }
#pragma unroll
    for (int k = 2; k <= 128; k <<= 1) {
#pragma unroll
        for (int j = k >> 1; j > 0; j >>= 1) {
            if (j == 64) {
                u64 lo = key[0] < key[1] ? key[0] : key[1];
                u64 hi = key[0] < key[1] ? key[1] : key[0];
                key[0] = lo; key[1] = hi;
            } else {
#pragma unroll
                for (int r = 0; r < 2; ++r) {
                    u64 o = shfl_xor_u64(key[r], j);
                    u32 ii = (u32)(r * 64 + lane);
                    bool dir = ((ii & (u32)k) == 0);
                    bool lower = ((ii & (u32)j) == 0);
                    bool keep_min = (dir == lower);
                    bool less = key[r] < o;
                    key[r] = (less == keep_min) ? key[r] : o;
                }
            }
        }
    }
    if (lane < KNN) {
        u64 m = key[0];
        if (m != ~0ULL) {
            float d2 = __uint_as_float((u32)(m >> 32));
            float d = __fsqrt_rn(d2);
            if (d < 10.0f) {
                float u = d * ((float)(NTAB - 1) / 10.0f);
                int i0 = (int)(u + 0.5f);          // nearest
                if (i0 > NTAB - 1) i0 = NTAB - 1;
                int jn = base + (int)(m & 0xffffffffu);
                int p = atomicAdd(&rev_cnt[jn], 1);
                rev_si[(size_t)jn * 128 + p] = make_int2(t, i0);
            }
        }
    }
}

// ---------------------------------------------------------------------------
// K4a: filter tables via MFMA (verified R15). Block = 128 table rows.
// ---------------------------------------------------------------------------
__launch_bounds__(256)
__global__ void vtab_kernel(const u16* __restrict__ mw1t,   // [6][128][64]
                            const u16* __restrict__ mw2t,   // [6][128][128]
                            const float* __restrict__ b1,   // [6][128]
                            const float* __restrict__ b2,   // [6][128]
                            u32* __restrict__ pk) {         // [6][NTAB][64]
    __shared__ u16 s_t1[128 * SA];
    int tid = threadIdx.x;
    int l = blockIdx.x / (NTAB / 128);
    int rbase = (blockIdx.x % (NTAB / 128)) * 128;
    const u16* w1 = mw1t + (size_t)l * 8192;
    const u16* w2 = mw2t + (size_t)l * 16384;

    int wv = tid >> 6, lane = tid & 63;
    int quad = lane >> 4, lr = lane & 15;
    int m0 = wv * 32;

    // Phase A: t1 = silu(rbf @ mw1 + b1), rbf per-lane in registers
    {
        const float wgi = 49.0f / 10.0f;
        const float dstep = 10.0f / (float)(NTAB - 1);
        U8 afr[2][2];
#pragma unroll
        for (int mt = 0; mt < 2; ++mt) {
            float d = (float)(rbase + m0 + mt * 16 + lr) * dstep;
            float u = d * wgi;
#pragma unroll
            for (int kki = 0; kki < 2; ++kki) {
                float t0 = u - (float)(quad * 8) - (float)(kki * 32);
                float vj[8];
#pragma unroll
                for (int j = 0; j < 8; ++j) {
                    float tt = t0 - (float)j;
                    float e = __expf(-0.5f * tt * tt);
                    if (kki == 1 && (quad * 8 + j) >= 18) e = 0.0f;  // k>=50 pad
                    vj[j] = e;
                }
#pragma unroll
                for (int p = 0; p < 4; ++p)
                    afr[mt][kki].w[p] = pkbf(vj[2 * p], vj[2 * p + 1]);
            }
        }
        f32x4 accA[2][8];
#pragma unroll
        for (int mt = 0; mt < 2; ++mt)
#pragma unroll
            for (int nt = 0; nt < 8; ++nt) accA[mt][nt] = (f32x4){0.f, 0.f, 0.f, 0.f};
#pragma unroll
        for (int kki = 0; kki < 2; ++kki) {
#pragma unroll
            for (int nt = 0; nt < 8; ++nt) {
                bf16x8 b = ldfrag(w1 + (nt * 16 + lr) * 64 + kki * 32 + quad * 8);
                accA[0][nt] = __builtin_amdgcn_mfma_f32_16x16x32_bf16(afr[0][kki].v, b, accA[0][nt], 0, 0, 0);
                accA[1][nt] = __builtin_amdgcn_mfma_f32_16x16x32_bf16(afr[1][kki].v, b, accA[1][nt], 0, 0, 0);
            }
        }
#pragma unroll
        for (int mt = 0; mt < 2; ++mt) {
            int r0 = m0 + mt * 16 + quad * 4;
            u16* tp0 = &s_t1[r0 * SA + lr];
#pragma unroll
            for (int nt = 0; nt < 8; ++nt) {
                int col = nt * 16;
                float bb = b1[l * 128 + col + lr];
                u32 p01 = pkbf(silu_f(accA[mt][nt][0] + bb),
                               silu_f(accA[mt][nt][1] + bb));
                u32 p23 = pkbf(silu_f(accA[mt][nt][2] + bb),
                               silu_f(accA[mt][nt][3] + bb));
                u16* tp = tp0 + col;
                tp[0]      = (u16)p01;
                tp[SA]     = (u16)(p01 >> 16);
                tp[2 * SA] = (u16)p23;
                tp[3 * SA] = (u16)(p23 >> 16);
            }
        }
    }
    // no barrier: Phase B reads only this wave's own 32 rows

    // Phase B: V = (t1 @ mw2 + b2) * cv(d), pair-packed bf16 out
    {
        f32x4 accB[2][8];
#pragma unroll
        for (int mt = 0; mt < 2; ++mt)
#pragma unroll
            for (int nt = 0; nt < 8; ++nt) accB[mt][nt] = (f32x4){0.f, 0.f, 0.f, 0.f};
#pragma unroll
        for (int kk = 0; kk < 128; kk += 32) {
            bf16x8 a0 = ldfrag(&s_t1[(m0 + lr)      * SA + kk + quad * 8]);
            bf16x8 a1 = ldfrag(&s_t1[(m0 + 16 + lr) * SA + kk + quad * 8]);
#pragma unroll
            for (int nt = 0; nt < 8; ++nt) {
                bf16x8 b = ldfrag(w2 + (nt * 16 + lr) * 128 + kk + quad * 8);
                accB[0][nt] = __builtin_amdgcn_mfma_f32_16x16x32_bf16(a0, b, accB[0][nt], 0, 0, 0);
                accB[1][nt] = __builtin_amdgcn_mfma_f32_16x16x32_bf16(a1, b, accB[1][nt], 0, 0, 0);
            }
        }
        const float dstep = 10.0f / (float)(NTAB - 1);
#pragma unroll
        for (int mt = 0; mt < 2; ++mt) {
            int r0 = m0 + mt * 16 + quad * 4;
            float cv[4];
#pragma unroll
            for (int r = 0; r < 4; ++r) {
                float d = (float)(rbase + r0 + r) * dstep;
                cv[r] = 0.5f * (cosf(d * 3.14159265f / 10.0f) + 1.0f);
            }
#pragma unroll
            for (int nt = 0; nt < 8; ++nt) {
                int col = nt * 16 + lr;
                float bb = b2[l * 128 + col];
#pragma unroll
                for (int r = 0; r < 4; ++r) {
                    float val = (accB[mt][nt][r] + bb) * cv[r];
                    float oth = __shfl_xor(val, 1, 64);
                    if ((lr & 1) == 0) {
                        int row = rbase + r0 + r;
                        pk[((size_t)l * NTAB + row) * 64 + (col >> 1)] =
                            pkbf(val, oth);
                    }
                }
            }
        }
    }
}

// ---------------------------------------------------------------------------
// K3a: initial gemm0 — xj(0) = emb[z] @ l1w(0) + b1(0), bf16 out.
// ---------------------------------------------------------------------------
__launch_bounds__(256)
__global__ void gemm0_kernel(const int* __restrict__ z,
                             const float* __restrict__ emb,
                             const u16* __restrict__ Bt,
                             const float* __restrict__ bias,
                             u16* __restrict__ xjb) {
    __shared__ u16 s_a[16 * SA];
    __shared__ float s_bias[128];
    int tid = threadIdx.x;
    int row0 = blockIdx.x * 16;
#pragma unroll
    for (int p = 0; p < 2; ++p) {
        int q = tid + p * 256;
        int r = q >> 5, c4 = (q & 31) * 4;
        const float* src = emb + (size_t)z[row0 + r] * 128;
        float4 v = *(const float4*)(src + c4);
        u32* d = (u32*)&s_a[r * SA + c4];
        d[0] = pkbf(v.x, v.y); d[1] = pkbf(v.z, v.w);
    }
    if (tid < 128) s_bias[tid] = bias[tid];
    __syncthreads();
    int wv = tid >> 6, lane = tid & 63;
    int quad = lane >> 4, lr = lane & 15;
    int n0 = wv * 32;
    f32x4 acc[2];
#pragma unroll
    for (int nt = 0; nt < 2; ++nt) acc[nt] = (f32x4){0.f, 0.f, 0.f, 0.f};
#pragma unroll
    for (int kk = 0; kk < 128; kk += 32) {
        bf16x8 a = ldfrag(&s_a[lr * SA + kk + quad * 8]);
#pragma unroll
        for (int nt = 0; nt < 2; ++nt) {
            bf16x8 b = ldfrag(Bt + (n0 + nt * 16 + lr) * 128 + kk + quad * 8);
            acc[nt] = __builtin_amdgcn_mfma_f32_16x16x32_bf16(a, b, acc[nt], 0, 0, 0);
        }
    }
#pragma unroll
    for (int nt = 0; nt < 2; ++nt)
#pragma unroll
        for (int r = 0; r < 4; ++r) {
            int col = n0 + nt * 16 + lr;
            xjb[(size_t)(row0 + quad * 4 + r) * 128 + col] =
                f2bf(acc[nt][r] + s_bias[col]);
        }
}

// ---------------------------------------------------------------------------
// K4c: aggregate — TWO receivers per wave (dual independent load streams,
// 32 loads in flight). Per-receiver math/order identical to R15.
// ---------------------------------------------------------------------------
__device__ __forceinline__ void agg_batch4(const int2* si, int it,
                                           const u32* pk, const u16* xjb,
                                           int lane, int c2,
                                           float& a0, float& a1, float& b0, float& b1,
                                           float& c0, float& c1, float& d0, float& d1) {
    u32 t[4], x[4];
#pragma unroll
    for (int q = 0; q < 4; ++q) {
        int2 s = si[it + q];
        t[q] = pk[(size_t)s.y * 64 + lane];
        x[q] = *(const u32*)(xjb + (size_t)s.x * 128 + c2);
    }
    a0 += bf2f((u16)t[0]) * bf2f((u16)x[0]);
    a1 += bf2f((u16)(t[0] >> 16)) * bf2f((u16)(x[0] >> 16));
    b0 += bf2f((u16)t[1]) * bf2f((u16)x[1]);
    b1 += bf2f((u16)(t[1] >> 16)) * bf2f((u16)(x[1] >> 16));
    c0 += bf2f((u16)t[2]) * bf2f((u16)x[2]);
    c1 += bf2f((u16)(t[2] >> 16)) * bf2f((u16)(x[2] >> 16));
    d0 += bf2f((u16)t[3]) * bf2f((u16)x[3]);
    d1 += bf2f((u16)(t[3] >> 16)) * bf2f((u16)(x[3] >> 16));
}

__launch_bounds__(256, 4)
__global__ void agg_kernel(const int* __restrict__ rev_cnt,
                           const int2* __restrict__ rev_si,
                           const u32* __restrict__ pk,
                           const u16* __restrict__ xjb,
                           float* __restrict__ agg) {
    int wv = threadIdx.x >> 6;
    int lane = threadIdx.x & 63;
    int jA = blockIdx.x * 8 + wv * 2;
    int jB = jA + 1;
    int degA = rev_cnt[jA], degB = rev_cnt[jB];
    const int2* siA = rev_si + (size_t)jA * 128;
    const int2* siB = rev_si + (size_t)jB * 128;
    int c2 = lane * 2;
    float Aa0=0,Aa1=0,Ab0=0,Ab1=0,Ac0=0,Ac1=0,Ad0=0,Ad1=0;
    float Ba0=0,Ba1=0,Bb0=0,Bb1=0,Bc0=0,Bc1=0,Bd0=0,Bd1=0;
    int itA = 0, itB = 0;
    // joint phase: both streams in flight
    while (itA + 4 <= degA && itB + 4 <= degB) {
        agg_batch4(siA, itA, pk, xjb, lane, c2, Aa0,Aa1,Ab0,Ab1,Ac0,Ac1,Ad0,Ad1);
        agg_batch4(siB, itB, pk, xjb, lane, c2, Ba0,Ba1,Bb0,Bb1,Bc0,Bc1,Bd0,Bd1);
        itA += 4; itB += 4;
    }
    for (; itA + 4 <= degA; itA += 4)
        agg_batch4(siA, itA, pk, xjb, lane, c2, Aa0,Aa1,Ab0,Ab1,Ac0,Ac1,Ad0,Ad1);
    for (; itB + 4 <= degB; itB += 4)
        agg_batch4(siB, itB, pk, xjb, lane, c2, Ba0,Ba1,Bb0,Bb1,Bc0,Bc1,Bd0,Bd1);
    for (; itA < degA; ++itA) {
        int2 s = siA[itA];
        u32 t = pk[(size_t)s.y * 64 + lane];
        u32 x = *(const u32*)(xjb + (size_t)s.x * 128 + c2);
        Aa0 += bf2f((u16)t) * bf2f((u16)x);
        Aa1 += bf2f((u16)(t >> 16)) * bf2f((u16)(x >> 16));
    }
    for (; itB < degB; ++itB) {
        int2 s = siB[itB];
        u32 t = pk[(size_t)s.y * 64 + lane];
        u32 x = *(const u32*)(xjb + (size_t)s.x * 128 + c2);
        Ba0 += bf2f((u16)t) * bf2f((u16)x);
        Ba1 += bf2f((u16)(t >> 16)) * bf2f((u16)(x >> 16));
    }
    float2 rA, rB;
    rA.x = (Aa0 + Ab0) + (Ac0 + Ad0);
    rA.y = (Aa1 + Ab1) + (Ac1 + Ad1);
    rB.x = (Ba0 + Bb0) + (Bc0 + Bd0);
    rB.y = (Ba1 + Bb1) + (Bc1 + Bd1);
    *(float2*)(agg + (size_t)jA * 128 + c2) = rA;
    *(float2*)(agg + (size_t)jB * 128 + c2) = rB;
}

// ---------------------------------------------------------------------------
// K3b: layer tail — h += silu(agg @ l2w + b2) [hi/lo split A]; then (unless
// LAST) xj(l+1) = h_new @ l1w(l+1) + b1(l+1). EMB=1: h_old = emb[z].
// ---------------------------------------------------------------------------
template <int EMB, int LAST>
__launch_bounds__(256)
__global__ void layer_tail_kernel(const float* __restrict__ agg,
                                  float* __restrict__ h,
                                  const int* __restrict__ z,
                                  const float* __restrict__ emb,
                                  const u16* __restrict__ B2t,
                                  const float* __restrict__ b2,
                                  const u16* __restrict__ B1n,
                                  const float* __restrict__ b1n,
                                  u16* __restrict__ xjb) {
    __shared__ u16 s_ahi[16 * SA];
    __shared__ u16 s_alo[16 * SA];
    __shared__ float s_h[16 * SH];
    __shared__ float s_b2[128], s_b1[128];
    int tid = threadIdx.x;
    int row0 = blockIdx.x * 16;
#pragma unroll
    for (int p = 0; p < 2; ++p) {
        int q = tid + p * 256;
        int r = q >> 5, c4 = (q & 31) * 4;
        float4 v = *(const float4*)(agg + (size_t)(row0 + r) * 128 + c4);
        u32 h0 = pkbf(v.x, v.y), h1 = pkbf(v.z, v.w);
        u32* hd = (u32*)&s_ahi[r * SA + c4];
        hd[0] = h0; hd[1] = h1;
        u32 l0 = pkbf(v.x - bf2f((u16)h0), v.y - bf2f((u16)(h0 >> 16)));
        u32 l1 = pkbf(v.z - bf2f((u16)h1), v.w - bf2f((u16)(h1 >> 16)));
        u32* ld = (u32*)&s_alo[r * SA + c4];
        ld[0] = l0; ld[1] = l1;
    }
    if (tid < 128) {
        s_b2[tid] = b2[tid];
        if (!LAST) s_b1[tid] = b1n[tid];
    }
    __syncthreads();

    int wv = tid >> 6, lane = tid & 63;
    int quad = lane >> 4, lr = lane & 15;
    int n0 = wv * 32;

    f32x4 acc[2];
#pragma unroll
    for (int nt = 0; nt < 2; ++nt) acc[nt] = (f32x4){0.f, 0.f, 0.f, 0.f};
#pragma unroll
    for (int kk = 0; kk < 128; kk += 32) {
        bf16x8 ah = ldfrag(&s_ahi[lr * SA + kk + quad * 8]);
        bf16x8 al = ldfrag(&s_alo[lr * SA + kk + quad * 8]);
#pragma unroll
        for (int nt = 0; nt < 2; ++nt) {
            bf16x8 b = ldfrag(B2t + (n0 + nt * 16 + lr) * 128 + kk + quad * 8);
            acc[nt] = __builtin_amdgcn_mfma_f32_16x16x32_bf16(ah, b, acc[nt], 0, 0, 0);
            acc[nt] = __builtin_amdgcn_mfma_f32_16x16x32_bf16(al, b, acc[nt], 0, 0, 0);
        }
    }
#pragma unroll
    for (int nt = 0; nt < 2; ++nt)
#pragma unroll
        for (int r = 0; r < 4; ++r) {
            int row = quad * 4 + r;
            int col = n0 + nt * 16 + lr;
            size_t off = (size_t)(row0 + row) * 128 + col;
            float hold = EMB ? emb[(size_t)z[row0 + row] * 128 + col] : h[off];
            float hn = hold + silu_f(acc[nt][r] + s_b2[col]);
            h[off] = hn;
            s_h[row * SH + col] = hn;
        }
    if (!LAST) {
        __syncthreads();
        f32x4 ac2[2];
#pragma unroll
        for (int nt = 0; nt < 2; ++nt) ac2[nt] = (f32x4){0.f, 0.f, 0.f, 0.f};
#pragma unroll
        for (int kk = 0; kk < 128; kk += 32) {
            const float* ap = &s_h[lr * SH + kk + quad * 8];
            float4 v0 = *(const float4*)ap;
            float4 v1 = *(const float4*)(ap + 4);
            U8 a;
            a.w[0] = pkbf(v0.x, v0.y); a.w[1] = pkbf(v0.z, v0.w);
            a.w[2] = pkbf(v1.x, v1.y); a.w[3] = pkbf(v1.z, v1.w);
#pragma unroll
            for (int nt = 0; nt < 2; ++nt) {
                bf16x8 b = ldfrag(B1n + (n0 + nt * 16 + lr) * 128 + kk + quad * 8);
                ac2[nt] = __builtin_amdgcn_mfma_f32_16x16x32_bf16(a.v, b, ac2[nt], 0, 0, 0);
            }
        }
#pragma unroll
        for (int nt = 0; nt < 2; ++nt)
#pragma unroll
            for (int r = 0; r < 4; ++r) {
                int col = n0 + nt * 16 + lr;
                xjb[(size_t)(row0 + quad * 4 + r) * 128 + col] =
                    f2bf(ac2[nt][r] + s_b1[col]);
            }
    }
}

// ---------------------------------------------------------------------------
// K6: output head — 16 atoms/block, LDS-tiled, one atomic per block.
// ---------------------------------------------------------------------------
__launch_bounds__(256)
__global__ void head_kernel(const float* __restrict__ h,
                            const float* __restrict__ ow1,
                            const float* __restrict__ ob1,
                            const float* __restrict__ ow2,
                            const float* __restrict__ ob2,
                            float* __restrict__ gsum) {
    __shared__ __align__(16) float s_w[128 * 64];
    __shared__ __align__(16) float s_h[16 * 132];
    __shared__ float s_sum;
    int tid = threadIdx.x;
    int a0 = blockIdx.x * 16;
    if (tid == 0) s_sum = 0.0f;
    {
        const float4* src = (const float4*)ow1;
        float4* dst = (float4*)s_w;
#pragma unroll
        for (int p = 0; p < 8; ++p) dst[tid + p * 256] = src[tid + p * 256];
    }
    {
        const float4* src = (const float4*)(h + (size_t)a0 * 128);
#pragma unroll
        for (int p = 0; p < 2; ++p) {
            int q = tid + p * 256;
            int r = q >> 5, c4 = (q & 31) * 4;
            *(float4*)&s_h[r * 132 + c4] = src[q];
        }
    }
    __syncthreads();
    int atom = tid >> 4, cg = tid & 15;
    const float* hr = &s_h[atom * 132];
    const float4* w4 = (const float4*)s_w;
    float4 acc = {0.f, 0.f, 0.f, 0.f};
#pragma unroll 8
    for (int f = 0; f < 128; ++f) {
        float hv = hr[f];
        float4 w = w4[f * 16 + cg];
        acc.x += hv * w.x; acc.y += hv * w.y;
        acc.z += hv * w.z; acc.w += hv * w.w;
    }
    int c0 = cg * 4;
    float v = silu_f(acc.x + ob1[c0 + 0]) * ow2[c0 + 0]
            + silu_f(acc.y + ob1[c0 + 1]) * ow2[c0 + 1]
            + silu_f(acc.z + ob1[c0 + 2]) * ow2[c0 + 2]
            + silu_f(acc.w + ob1[c0 + 3]) * ow2[c0 + 3];
    v += __shfl_xor(v, 1, 64);
    v += __shfl_xor(v, 2, 64);
    v += __shfl_xor(v, 4, 64);
    v += __shfl_xor(v, 8, 64);
    if ((tid & 15) == 0) atomicAdd(&s_sum, v + ob2[0]);
    __syncthreads();
    if (tid == 0) atomicAdd(&gsum[a0 >> 7], s_sum);
}

__global__ void finalize_kernel(const float* __restrict__ gsum, void* __restrict__ out,
                                const int* __restrict__ flag) {
    int t = threadIdx.x;
    if (*flag) ((float*)out)[t] = gsum[t];
    else       ((u16*)out)[t]   = f2bf(gsum[t]);
}

// ---------------------------------------------------------------------------
extern "C" void kernel_launch(void* const* d_in, const int* in_sizes, int n_in,
                              void* d_out, int out_size, void* d_ws, size_t ws_size,
                              hipStream_t stream) {
    const void* pos  = d_in[0];
    const int*  z    = (const int*)d_in[1];
    // d_in[2] = batch (implicit: graph = i >> 7)
    const void* emb  = d_in[3];
    const void* mw1  = d_in[4];
    const void* mb1  = d_in[5];
    const void* mw2  = d_in[6];
    const void* mb2  = d_in[7];
    const void* l1w  = d_in[8];
    const void* l1b  = d_in[9];
    const void* l2w  = d_in[10];
    const void* l2b  = d_in[11];
    const void* ow1  = d_in[12];
    const void* ob1  = d_in[13];
    const void* ow2  = d_in[14];
    const void* ob2  = d_in[15];

    char* ws = (char*)d_ws;
    const size_t KB = 1024, MB = 1048576;
    int*   w_flag  = (int*)  (ws);
    float* c_pos   = (float*)(ws + 4   * KB);
    float* c_emb   = (float*)(ws + 112 * KB);
    float* c_mb1   = (float*)(ws + 168 * KB);
    float* c_mb2   = (float*)(ws + 176 * KB);
    float* c_l1b   = (float*)(ws + 184 * KB);
    float* c_l2b   = (float*)(ws + 192 * KB);
    float* c_ow1   = (float*)(ws + 200 * KB);
    float* c_ob1   = (float*)(ws + 236 * KB);
    float* c_ow2   = (float*)(ws + 240 * KB);
    float* c_ob2   = (float*)(ws + 244 * KB);
    float* w_gsum  = (float*)(ws + 248 * KB);
    u16*   c_l1wt  = (u16*)  (ws + 256 * KB);   // 192 KB
    u16*   c_l2wt  = (u16*)  (ws + 448 * KB);   // 192 KB
    u16*   c_mw2t  = (u16*)  (ws + 640 * KB);   // 192 KB
    u16*   c_mw1t  = (u16*)  (ws + 832 * KB);   // 96 KB
    int*   rev_cnt = (int*)  (ws + 2  * MB);    // 32 KB
    int2*  rev_si  = (int2*) (ws + 3  * MB);    // 8 MB
    float* w_h     = (float*)(ws + 11 * MB);    // 4 MB
    u16*   w_xjb   = (u16*)  (ws + 15 * MB);    // 2 MB
    float* w_agg   = (float*)(ws + 17 * MB);    // 4 MB
    u32*   w_pk    = (u32*)  (ws + 21 * MB);    // 6 MB

    probe_kernel<<<1, 256, 0, stream>>>((const u16*)emb, w_flag, rev_cnt, w_gsum);

    IngestDesc dsc;
    const void* srcs[NARR] = {pos, emb, mb1, mb2, l1b, l2b, ow1, ob1, ow2, ob2};
    void* dsts[NARR] = {c_pos, c_emb, c_mb1, c_mb2, c_l1b, c_l2b, c_ow1, c_ob1,
                        c_ow2, c_ob2};
    int ns_[NARR] = {24576, 12800, 768, 768, 768, 768, 8192, 64, 64, 1};
    int total = 0;
    for (int a = 0; a < NARR; ++a) {
        dsc.src[a] = srcs[a]; dsc.dst[a] = dsts[a]; dsc.n[a] = ns_[a];
        total += ns_[a];
    }
    ingest_kernel<<<(total + 255) / 256, 256, 0, stream>>>(dsc, w_flag, total);
    prep_weights<<<1344, 256, 0, stream>>>(l1w, l2w, mw2, mw1,
                                           c_l1wt, c_l2wt, c_mw2t, c_mw1t, w_flag);

    build_graph_kernel<<<NATOMS / 4, 256, 0, stream>>>(c_pos, rev_cnt, rev_si);
    vtab_kernel<<<LAYERS * NTAB / 128, 256, 0, stream>>>(
        c_mw1t, c_mw2t, c_mb1, c_mb2, w_pk);

    gemm0_kernel<<<NATOMS / 16, 256, 0, stream>>>(z, c_emb, c_l1wt, c_l1b, w_xjb);

    for (int l = 0; l < LAYERS; ++l) {
        agg_kernel<<<NATOMS / 8, 256, 0, stream>>>(
            rev_cnt, rev_si, w_pk + (size_t)l * NTAB * 64, w_xjb, w_agg);
        const u16* B2 = c_l2wt + (size_t)l * 16384;
        const float* b2 = c_l2b + (size_t)l * 128;
        const u16* B1n = c_l1wt + (size_t)(l + 1) * 16384;
        const float* b1n = c_l1b + (size_t)(l + 1) * 128;
        if (l == 0)
            layer_tail_kernel<1, 0><<<NATOMS / 16, 256, 0, stream>>>(
                w_agg, w_h, z, c_emb, B2, b2, B1n, b1n, w_xjb);
        else if (l < LAYERS - 1)
            layer_tail_kernel<0, 0><<<NATOMS / 16, 256, 0, stream>>>(
                w_agg, w_h, z, c_emb, B2, b2, B1n, b1n, w_xjb);
        else
            layer_tail_kernel<0, 1><<<NATOMS / 16, 256, 0, stream>>>(
                w_agg, w_h, z, c_emb, B2, b2, nullptr, nullptr, nullptr);
    }

    head_kernel<<<NATOMS / 16, 256, 0, stream>>>(w_h, c_ow1, c_ob1, c_ow2, c_ob2,
                                                 w_gsum);
    finalize_kernel<<<1, GRAPHS, 0, stream>>>(w_gsum, (void*)d_out, w_flag);
}

// Round 17
// 287.651 us; speedup vs baseline: 1.0338x; 1.0338x over previous
//
#include <hip/hip_runtime.h>
#include <math.h>

typedef unsigned short u16;
typedef unsigned int   u32;
typedef unsigned long long u64;

#define NATOMS 8192
#define GRAPHS 64
#define APG    128
#define KNN    32
#define NGAUSS 50
#define HID    128
#define LAYERS 6
#define NTAB   4096
#define SA     136   // u16 stride, 272B rows (16B-aligned)
#define SH     132   // f32 stride, 528B rows (16B-aligned)

typedef __attribute__((ext_vector_type(8))) short bf16x8;
typedef __attribute__((ext_vector_type(4))) float f32x4;

__device__ __forceinline__ float bf2f(u16 v) {
    return __uint_as_float(((u32)v) << 16);
}
__device__ __forceinline__ u16 f2bf(float f) {
    u32 u = __float_as_uint(f);
    u32 lsb = (u >> 16) & 1u;
    u += 0x7fffu + lsb;
    return (u16)(u >> 16);
}
__device__ __forceinline__ u32 pkbf(float lo, float hi) {
#if __has_builtin(__builtin_amdgcn_cvt_pk_bf16_f32)
    auto r = __builtin_amdgcn_cvt_pk_bf16_f32(lo, hi);
    u32 u; __builtin_memcpy(&u, &r, 4); return u;
#else
    return (u32)f2bf(lo) | ((u32)f2bf(hi) << 16);
#endif
}
__device__ __forceinline__ float silu_f(float x) {
    return x * __builtin_amdgcn_rcpf(1.0f + __expf(-x));
}
__device__ __forceinline__ bf16x8 ldfrag(const u16* p) {
    return *(const bf16x8*)__builtin_assume_aligned(p, 16);
}
__device__ __forceinline__ u64 shfl_xor_u64(u64 v, int mask) {
    u32 lo = (u32)v, hi = (u32)(v >> 32);
    lo = (u32)__shfl_xor((int)lo, mask, 64);
    hi = (u32)__shfl_xor((int)hi, mask, 64);
    return ((u64)hi << 32) | lo;
}
union U8 { bf16x8 v; u32 w[4]; };

// ---------------------------------------------------------------------------
// K0: dtype probe + zero rev_cnt/gsum (folds 2 memset dispatches).
// ---------------------------------------------------------------------------
__global__ void probe_kernel(const u16* __restrict__ raw, int* __restrict__ flag,
                             int* __restrict__ rev_cnt, float* __restrict__ gsum) {
    __shared__ int s;
    int t = threadIdx.x;
    if (t == 0) s = 0;
    __syncthreads();
    float x = bf2f(raw[2 * t]);
    if (!(fabsf(x) < 1000.0f)) atomicOr(&s, 1);
    for (int i = t; i < NATOMS; i += 256) rev_cnt[i] = 0;
    if (t < GRAPHS) gsum[t] = 0.0f;
    __syncthreads();
    if (t == 0) *flag = s;
}

// ---------------------------------------------------------------------------
// K0b: ingest fp32-canonical copies (small arrays only).
// ---------------------------------------------------------------------------
#define NARR 10
struct IngestDesc {
    const void* src[NARR];
    void*       dst[NARR];
    int         n[NARR];
};

__global__ void ingest_kernel(IngestDesc d, const int* __restrict__ flag, int total) {
    int gid = blockIdx.x * blockDim.x + threadIdx.x;
    if (gid >= total) return;
    int a = 0, off = gid;
    while (off >= d.n[a]) { off -= d.n[a]; ++a; }
    bool f32in = (*flag != 0);
    float v = f32in ? ((const float*)d.src[a])[off]
                    : bf2f(((const u16*)d.src[a])[off]);
    ((float*)d.dst[a])[off] = v;
}

// ---------------------------------------------------------------------------
// K0c: weight prep — transpose l1w/l2w/mw2 to [n][k] bf16; mw1 -> [n][64]
// (k>=50 zero-padded). All are MFMA B-operands.
// ---------------------------------------------------------------------------
__global__ void prep_weights(const void* __restrict__ l1w, const void* __restrict__ l2w,
                             const void* __restrict__ mw2, const void* __restrict__ mw1,
                             u16* __restrict__ l1wt, u16* __restrict__ l2wt,
                             u16* __restrict__ mw2t, u16* __restrict__ mw1t,
                             const int* __restrict__ flag) {
    int gid = blockIdx.x * blockDim.x + threadIdx.x;
    bool f32in = (*flag != 0);
    if (gid < 3 * 98304) {
        int seg = gid / 98304;
        int t = gid % 98304;
        int l = t >> 14;
        int n = (t >> 7) & 127;
        int k = t & 127;
        const void* src = (seg == 0) ? l1w : ((seg == 1) ? l2w : mw2);
        u16* dst = (seg == 0) ? l1wt : ((seg == 1) ? l2wt : mw2t);
        int si = l * 16384 + k * 128 + n;
        float v = f32in ? ((const float*)src)[si] : bf2f(((const u16*)src)[si]);
        dst[t] = f2bf(v);
    } else {
        int t = gid - 3 * 98304;
        if (t < 49152) {
            int l = t >> 13;
            int n = (t >> 6) & 127;
            int k = t & 63;
            float v = 0.0f;
            if (k < 50) {
                int si = l * 6400 + k * 128 + n;
                v = f32in ? ((const float*)mw1)[si] : bf2f(((const u16*)mw1)[si]);
            }
            mw1t[t] = f2bf(v);
        }
    }
}

// ---------------------------------------------------------------------------
// K1: graph build + edge prep. One WAVE per center; full bitonic sort of 128
// (d2,j) u64 keys (verified R10-R16). Valid edges -> receiver lists with
// (src atom, NEAREST table row index).
// ---------------------------------------------------------------------------
__launch_bounds__(256)
__global__ void build_graph_kernel(const float* __restrict__ pos,
                                   int* __restrict__ rev_cnt,
                                   int2* __restrict__ rev_si) {
    int wv = threadIdx.x >> 6, lane = threadIdx.x & 63;
    int t = blockIdx.x * 4 + wv;
    int tl = t & 127;
    int base = t & ~127;
    float cx = pos[t * 3 + 0];
    float cy = pos[t * 3 + 1];
    float cz = pos[t * 3 + 2];
    u64 key[2];
#pragma unroll
    for (int c = 0; c < 2; ++c) {
        int j = lane + c * 64;
        float jx = pos[(base + j) * 3 + 0];
        float jy = pos[(base + j) * 3 + 1];
        float jz = pos[(base + j) * 3 + 2];
        float dx = __fsub_rn(cx, jx);
        float dy = __fsub_rn(cy, jy);
        float dz = __fsub_rn(cz, jz);
        float d2 = __fadd_rn(__fadd_rn(__fmul_rn(dx, dx), __fmul_rn(dy, dy)),
                             __fmul_rn(dz, dz));
        bool valid = (j != tl) && (d2 < 100.0f);
        key[c] = valid ? ((((u64)__float_as_uint(d2)) << 32) | (u32)j) : ~0ULL;
    }
#pragma unroll
    for (int k = 2; k <= 128; k <<= 1) {
#pragma unroll
        for (int j = k >> 1; j > 0; j >>= 1) {
            if (j == 64) {
                u64 lo = key[0] < key[1] ? key[0] : key[1];
                u64 hi = key[0] < key[1] ? key[1] : key[0];
                key[0] = lo; key[1] = hi;
            } else {
#pragma unroll
                for (int r = 0; r < 2; ++r) {
                    u64 o = shfl_xor_u64(key[r], j);
                    u32 ii = (u32)(r * 64 + lane);
                    bool dir = ((ii & (u32)k) == 0);
                    bool lower = ((ii & (u32)j) == 0);
                    bool keep_min = (dir == lower);
                    bool less = key[r] < o;
                    key[r] = (less == keep_min) ? key[r] : o;
                }
            }
        }
    }
    if (lane < KNN) {
        u64 m = key[0];
        if (m != ~0ULL) {
            float d2 = __uint_as_float((u32)(m >> 32));
            float d = __fsqrt_rn(d2);
            if (d < 10.0f) {
                float u = d * ((float)(NTAB - 1) / 10.0f);
                int i0 = (int)(u + 0.5f);          // nearest
                if (i0 > NTAB - 1) i0 = NTAB - 1;
                int jn = base + (int)(m & 0xffffffffu);
                int p = atomicAdd(&rev_cnt[jn], 1);
                rev_si[(size_t)jn * 128 + p] = make_int2(t, i0);
            }
        }
    }
}

// ---------------------------------------------------------------------------
// K4a: filter tables via MFMA (verified R15). Block = 128 table rows.
// ---------------------------------------------------------------------------
__launch_bounds__(256)
__global__ void vtab_kernel(const u16* __restrict__ mw1t,   // [6][128][64]
                            const u16* __restrict__ mw2t,   // [6][128][128]
                            const float* __restrict__ b1,   // [6][128]
                            const float* __restrict__ b2,   // [6][128]
                            u32* __restrict__ pk) {         // [6][NTAB][64]
    __shared__ u16 s_t1[128 * SA];
    int tid = threadIdx.x;
    int l = blockIdx.x / (NTAB / 128);
    int rbase = (blockIdx.x % (NTAB / 128)) * 128;
    const u16* w1 = mw1t + (size_t)l * 8192;
    const u16* w2 = mw2t + (size_t)l * 16384;

    int wv = tid >> 6, lane = tid & 63;
    int quad = lane >> 4, lr = lane & 15;
    int m0 = wv * 32;

    // Phase A: t1 = silu(rbf @ mw1 + b1), rbf per-lane in registers
    {
        const float wgi = 49.0f / 10.0f;
        const float dstep = 10.0f / (float)(NTAB - 1);
        U8 afr[2][2];
#pragma unroll
        for (int mt = 0; mt < 2; ++mt) {
            float d = (float)(rbase + m0 + mt * 16 + lr) * dstep;
            float u = d * wgi;
#pragma unroll
            for (int kki = 0; kki < 2; ++kki) {
                float t0 = u - (float)(quad * 8) - (float)(kki * 32);
                float vj[8];
#pragma unroll
                for (int j = 0; j < 8; ++j) {
                    float tt = t0 - (float)j;
                    float e = __expf(-0.5f * tt * tt);
                    if (kki == 1 && (quad * 8 + j) >= 18) e = 0.0f;  // k>=50 pad
                    vj[j] = e;
                }
#pragma unroll
                for (int p = 0; p < 4; ++p)
                    afr[mt][kki].w[p] = pkbf(vj[2 * p], vj[2 * p + 1]);
            }
        }
        f32x4 accA[2][8];
#pragma unroll
        for (int mt = 0; mt < 2; ++mt)
#pragma unroll
            for (int nt = 0; nt < 8; ++nt) accA[mt][nt] = (f32x4){0.f, 0.f, 0.f, 0.f};
#pragma unroll
        for (int kki = 0; kki < 2; ++kki) {
#pragma unroll
            for (int nt = 0; nt < 8; ++nt) {
                bf16x8 b = ldfrag(w1 + (nt * 16 + lr) * 64 + kki * 32 + quad * 8);
                accA[0][nt] = __builtin_amdgcn_mfma_f32_16x16x32_bf16(afr[0][kki].v, b, accA[0][nt], 0, 0, 0);
                accA[1][nt] = __builtin_amdgcn_mfma_f32_16x16x32_bf16(afr[1][kki].v, b, accA[1][nt], 0, 0, 0);
            }
        }
#pragma unroll
        for (int mt = 0; mt < 2; ++mt) {
            int r0 = m0 + mt * 16 + quad * 4;
            u16* tp0 = &s_t1[r0 * SA + lr];
#pragma unroll
            for (int nt = 0; nt < 8; ++nt) {
                int col = nt * 16;
                float bb = b1[l * 128 + col + lr];
                u32 p01 = pkbf(silu_f(accA[mt][nt][0] + bb),
                               silu_f(accA[mt][nt][1] + bb));
                u32 p23 = pkbf(silu_f(accA[mt][nt][2] + bb),
                               silu_f(accA[mt][nt][3] + bb));
                u16* tp = tp0 + col;
                tp[0]      = (u16)p01;
                tp[SA]     = (u16)(p01 >> 16);
                tp[2 * SA] = (u16)p23;
                tp[3 * SA] = (u16)(p23 >> 16);
            }
        }
    }
    // no barrier: Phase B reads only this wave's own 32 rows

    // Phase B: V = (t1 @ mw2 + b2) * cv(d), pair-packed bf16 out
    {
        f32x4 accB[2][8];
#pragma unroll
        for (int mt = 0; mt < 2; ++mt)
#pragma unroll
            for (int nt = 0; nt < 8; ++nt) accB[mt][nt] = (f32x4){0.f, 0.f, 0.f, 0.f};
#pragma unroll
        for (int kk = 0; kk < 128; kk += 32) {
            bf16x8 a0 = ldfrag(&s_t1[(m0 + lr)      * SA + kk + quad * 8]);
            bf16x8 a1 = ldfrag(&s_t1[(m0 + 16 + lr) * SA + kk + quad * 8]);
#pragma unroll
            for (int nt = 0; nt < 8; ++nt) {
                bf16x8 b = ldfrag(w2 + (nt * 16 + lr) * 128 + kk + quad * 8);
                accB[0][nt] = __builtin_amdgcn_mfma_f32_16x16x32_bf16(a0, b, accB[0][nt], 0, 0, 0);
                accB[1][nt] = __builtin_amdgcn_mfma_f32_16x16x32_bf16(a1, b, accB[1][nt], 0, 0, 0);
            }
        }
        const float dstep = 10.0f / (float)(NTAB - 1);
#pragma unroll
        for (int mt = 0; mt < 2; ++mt) {
            int r0 = m0 + mt * 16 + quad * 4;
            float cv[4];
#pragma unroll
            for (int r = 0; r < 4; ++r) {
                float d = (float)(rbase + r0 + r) * dstep;
                cv[r] = 0.5f * (cosf(d * 3.14159265f / 10.0f) + 1.0f);
            }
#pragma unroll
            for (int nt = 0; nt < 8; ++nt) {
                int col = nt * 16 + lr;
                float bb = b2[l * 128 + col];
#pragma unroll
                for (int r = 0; r < 4; ++r) {
                    float val = (accB[mt][nt][r] + bb) * cv[r];
                    float oth = __shfl_xor(val, 1, 64);
                    if ((lr & 1) == 0) {
                        int row = rbase + r0 + r;
                        pk[((size_t)l * NTAB + row) * 64 + (col >> 1)] =
                            pkbf(val, oth);
                    }
                }
            }
        }
    }
}

// ---------------------------------------------------------------------------
// K3a: initial gemm0 — xj(0) = emb[z] @ l1w(0) + b1(0), bf16 out.
// ---------------------------------------------------------------------------
__launch_bounds__(256)
__global__ void gemm0_kernel(const int* __restrict__ z,
                             const float* __restrict__ emb,
                             const u16* __restrict__ Bt,
                             const float* __restrict__ bias,
                             u16* __restrict__ xjb) {
    __shared__ u16 s_a[16 * SA];
    __shared__ float s_bias[128];
    int tid = threadIdx.x;
    int row0 = blockIdx.x * 16;
#pragma unroll
    for (int p = 0; p < 2; ++p) {
        int q = tid + p * 256;
        int r = q >> 5, c4 = (q & 31) * 4;
        const float* src = emb + (size_t)z[row0 + r] * 128;
        float4 v = *(const float4*)(src + c4);
        u32* d = (u32*)&s_a[r * SA + c4];
        d[0] = pkbf(v.x, v.y); d[1] = pkbf(v.z, v.w);
    }
    if (tid < 128) s_bias[tid] = bias[tid];
    __syncthreads();
    int wv = tid >> 6, lane = tid & 63;
    int quad = lane >> 4, lr = lane & 15;
    int n0 = wv * 32;
    f32x4 acc[2];
#pragma unroll
    for (int nt = 0; nt < 2; ++nt) acc[nt] = (f32x4){0.f, 0.f, 0.f, 0.f};
#pragma unroll
    for (int kk = 0; kk < 128; kk += 32) {
        bf16x8 a = ldfrag(&s_a[lr * SA + kk + quad * 8]);
#pragma unroll
        for (int nt = 0; nt < 2; ++nt) {
            bf16x8 b = ldfrag(Bt + (n0 + nt * 16 + lr) * 128 + kk + quad * 8);
            acc[nt] = __builtin_amdgcn_mfma_f32_16x16x32_bf16(a, b, acc[nt], 0, 0, 0);
        }
    }
#pragma unroll
    for (int nt = 0; nt < 2; ++nt)
#pragma unroll
        for (int r = 0; r < 4; ++r) {
            int col = n0 + nt * 16 + lr;
            xjb[(size_t)(row0 + quad * 4 + r) * 128 + col] =
                f2bf(acc[nt][r] + s_bias[col]);
        }
}

// ---------------------------------------------------------------------------
// K4c: aggregate (R15-proven form). One wave per receiver; NEAREST table
// (4B/lane/edge) + bf16 xj (4B); fp32 accumulate; 8-wide unroll.
// ---------------------------------------------------------------------------
__launch_bounds__(256, 4)
__global__ void agg_kernel(const int* __restrict__ rev_cnt,
                           const int2* __restrict__ rev_si,
                           const u32* __restrict__ pk,
                           const u16* __restrict__ xjb,
                           float* __restrict__ agg) {
    int j = blockIdx.x * 4 + (threadIdx.x >> 6);
    int lane = threadIdx.x & 63;
    int deg = rev_cnt[j];
    const int2* si = rev_si + (size_t)j * 128;
    int c2 = lane * 2;
    float a0 = 0.f, a1 = 0.f, b0 = 0.f, b1 = 0.f;
    float c0 = 0.f, c1 = 0.f, d0 = 0.f, d1 = 0.f;
    int it = 0;
    for (; it + 8 <= deg; it += 8) {
        u32 t[8], x[8];
#pragma unroll
        for (int q = 0; q < 8; ++q) {
            int2 s = si[it + q];
            t[q] = pk[(size_t)s.y * 64 + lane];
            x[q] = *(const u32*)(xjb + (size_t)s.x * 128 + c2);
        }
#pragma unroll
        for (int q = 0; q < 8; ++q) {
            float v0 = bf2f((u16)t[q]) * bf2f((u16)x[q]);
            float v1 = bf2f((u16)(t[q] >> 16)) * bf2f((u16)(x[q] >> 16));
            switch (q & 3) {
                case 0: a0 += v0; a1 += v1; break;
                case 1: b0 += v0; b1 += v1; break;
                case 2: c0 += v0; c1 += v1; break;
                default: d0 += v0; d1 += v1; break;
            }
        }
    }
    for (; it + 4 <= deg; it += 4) {
        u32 t[4], x[4];
#pragma unroll
        for (int q = 0; q < 4; ++q) {
            int2 s = si[it + q];
            t[q] = pk[(size_t)s.y * 64 + lane];
            x[q] = *(const u32*)(xjb + (size_t)s.x * 128 + c2);
        }
#pragma unroll
        for (int q = 0; q < 4; ++q) {
            float v0 = bf2f((u16)t[q]) * bf2f((u16)x[q]);
            float v1 = bf2f((u16)(t[q] >> 16)) * bf2f((u16)(x[q] >> 16));
            if (q == 0) { a0 += v0; a1 += v1; }
            else if (q == 1) { b0 += v0; b1 += v1; }
            else if (q == 2) { c0 += v0; c1 += v1; }
            else { d0 += v0; d1 += v1; }
        }
    }
    for (; it < deg; ++it) {
        int2 s = si[it];
        u32 t = pk[(size_t)s.y * 64 + lane];
        u32 x = *(const u32*)(xjb + (size_t)s.x * 128 + c2);
        a0 += bf2f((u16)t) * bf2f((u16)x);
        a1 += bf2f((u16)(t >> 16)) * bf2f((u16)(x >> 16));
    }
    float2 r;
    r.x = (a0 + b0) + (c0 + d0);
    r.y = (a1 + b1) + (c1 + d1);
    *(float2*)(agg + (size_t)j * 128 + c2) = r;
}

// ---------------------------------------------------------------------------
// K3b: layer tail — h += silu(agg @ l2w + b2) [hi/lo split A]; then (unless
// LAST) xj(l+1) = h_new @ l1w(l+1) + b1(l+1). EMB=1: h_old = emb[z].
// ---------------------------------------------------------------------------
template <int EMB, int LAST>
__launch_bounds__(256)
__global__ void layer_tail_kernel(const float* __restrict__ agg,
                                  float* __restrict__ h,
                                  const int* __restrict__ z,
                                  const float* __restrict__ emb,
                                  const u16* __restrict__ B2t,
                                  const float* __restrict__ b2,
                                  const u16* __restrict__ B1n,
                                  const float* __restrict__ b1n,
                                  u16* __restrict__ xjb) {
    __shared__ u16 s_ahi[16 * SA];
    __shared__ u16 s_alo[16 * SA];
    __shared__ float s_h[16 * SH];
    __shared__ float s_b2[128], s_b1[128];
    int tid = threadIdx.x;
    int row0 = blockIdx.x * 16;
#pragma unroll
    for (int p = 0; p < 2; ++p) {
        int q = tid + p * 256;
        int r = q >> 5, c4 = (q & 31) * 4;
        float4 v = *(const float4*)(agg + (size_t)(row0 + r) * 128 + c4);
        u32 h0 = pkbf(v.x, v.y), h1 = pkbf(v.z, v.w);
        u32* hd = (u32*)&s_ahi[r * SA + c4];
        hd[0] = h0; hd[1] = h1;
        u32 l0 = pkbf(v.x - bf2f((u16)h0), v.y - bf2f((u16)(h0 >> 16)));
        u32 l1 = pkbf(v.z - bf2f((u16)h1), v.w - bf2f((u16)(h1 >> 16)));
        u32* ld = (u32*)&s_alo[r * SA + c4];
        ld[0] = l0; ld[1] = l1;
    }
    if (tid < 128) {
        s_b2[tid] = b2[tid];
        if (!LAST) s_b1[tid] = b1n[tid];
    }
    __syncthreads();

    int wv = tid >> 6, lane = tid & 63;
    int quad = lane >> 4, lr = lane & 15;
    int n0 = wv * 32;

    f32x4 acc[2];
#pragma unroll
    for (int nt = 0; nt < 2; ++nt) acc[nt] = (f32x4){0.f, 0.f, 0.f, 0.f};
#pragma unroll
    for (int kk = 0; kk < 128; kk += 32) {
        bf16x8 ah = ldfrag(&s_ahi[lr * SA + kk + quad * 8]);
        bf16x8 al = ldfrag(&s_alo[lr * SA + kk + quad * 8]);
#pragma unroll
        for (int nt = 0; nt < 2; ++nt) {
            bf16x8 b = ldfrag(B2t + (n0 + nt * 16 + lr) * 128 + kk + quad * 8);
            acc[nt] = __builtin_amdgcn_mfma_f32_16x16x32_bf16(ah, b, acc[nt], 0, 0, 0);
            acc[nt] = __builtin_amdgcn_mfma_f32_16x16x32_bf16(al, b, acc[nt], 0, 0, 0);
        }
    }
#pragma unroll
    for (int nt = 0; nt < 2; ++nt)
#pragma unroll
        for (int r = 0; r < 4; ++r) {
            int row = quad * 4 + r;
            int col = n0 + nt * 16 + lr;
            size_t off = (size_t)(row0 + row) * 128 + col;
            float hold = EMB ? emb[(size_t)z[row0 + row] * 128 + col] : h[off];
            float hn = hold + silu_f(acc[nt][r] + s_b2[col]);
            h[off] = hn;
            s_h[row * SH + col] = hn;
        }
    if (!LAST) {
        __syncthreads();
        f32x4 ac2[2];
#pragma unroll
        for (int nt = 0; nt < 2; ++nt) ac2[nt] = (f32x4){0.f, 0.f, 0.f, 0.f};
#pragma unroll
        for (int kk = 0; kk < 128; kk += 32) {
            const float* ap = &s_h[lr * SH + kk + quad * 8];
            float4 v0 = *(const float4*)ap;
            float4 v1 = *(const float4*)(ap + 4);
            U8 a;
            a.w[0] = pkbf(v0.x, v0.y); a.w[1] = pkbf(v0.z, v0.w);
            a.w[2] = pkbf(v1.x, v1.y); a.w[3] = pkbf(v1.z, v1.w);
#pragma unroll
            for (int nt = 0; nt < 2; ++nt) {
                bf16x8 b = ldfrag(B1n + (n0 + nt * 16 + lr) * 128 + kk + quad * 8);
                ac2[nt] = __builtin_amdgcn_mfma_f32_16x16x32_bf16(a.v, b, ac2[nt], 0, 0, 0);
            }
        }
#pragma unroll
        for (int nt = 0; nt < 2; ++nt)
#pragma unroll
            for (int r = 0; r < 4; ++r) {
                int col = n0 + nt * 16 + lr;
                xjb[(size_t)(row0 + quad * 4 + r) * 128 + col] =
                    f2bf(ac2[nt][r] + s_b1[col]);
            }
    }
}

// ---------------------------------------------------------------------------
// K6: output head — 16 atoms/block, LDS-tiled, one atomic per block.
// ---------------------------------------------------------------------------
__launch_bounds__(256)
__global__ void head_kernel(const float* __restrict__ h,
                            const float* __restrict__ ow1,
                            const float* __restrict__ ob1,
                            const float* __restrict__ ow2,
                            const float* __restrict__ ob2,
                            float* __restrict__ gsum) {
    __shared__ __align__(16) float s_w[128 * 64];
    __shared__ __align__(16) float s_h[16 * 132];
    __shared__ float s_sum;
    int tid = threadIdx.x;
    int a0 = blockIdx.x * 16;
    if (tid == 0) s_sum = 0.0f;
    {
        const float4* src = (const float4*)ow1;
        float4* dst = (float4*)s_w;
#pragma unroll
        for (int p = 0; p < 8; ++p) dst[tid + p * 256] = src[tid + p * 256];
    }
    {
        const float4* src = (const float4*)(h + (size_t)a0 * 128);
#pragma unroll
        for (int p = 0; p < 2; ++p) {
            int q = tid + p * 256;
            int r = q >> 5, c4 = (q & 31) * 4;
            *(float4*)&s_h[r * 132 + c4] = src[q];
        }
    }
    __syncthreads();
    int atom = tid >> 4, cg = tid & 15;
    const float* hr = &s_h[atom * 132];
    const float4* w4 = (const float4*)s_w;
    float4 acc = {0.f, 0.f, 0.f, 0.f};
#pragma unroll 8
    for (int f = 0; f < 128; ++f) {
        float hv = hr[f];
        float4 w = w4[f * 16 + cg];
        acc.x += hv * w.x; acc.y += hv * w.y;
        acc.z += hv * w.z; acc.w += hv * w.w;
    }
    int c0 = cg * 4;
    float v = silu_f(acc.x + ob1[c0 + 0]) * ow2[c0 + 0]
            + silu_f(acc.y + ob1[c0 + 1]) * ow2[c0 + 1]
            + silu_f(acc.z + ob1[c0 + 2]) * ow2[c0 + 2]
            + silu_f(acc.w + ob1[c0 + 3]) * ow2[c0 + 3];
    v += __shfl_xor(v, 1, 64);
    v += __shfl_xor(v, 2, 64);
    v += __shfl_xor(v, 4, 64);
    v += __shfl_xor(v, 8, 64);
    if ((tid & 15) == 0) atomicAdd(&s_sum, v + ob2[0]);
    __syncthreads();
    if (tid == 0) atomicAdd(&gsum[a0 >> 7], s_sum);
}

__global__ void finalize_kernel(const float* __restrict__ gsum, void* __restrict__ out,
                                const int* __restrict__ flag) {
    int t = threadIdx.x;
    if (*flag) ((float*)out)[t] = gsum[t];
    else       ((u16*)out)[t]   = f2bf(gsum[t]);
}

// ---------------------------------------------------------------------------
extern "C" void kernel_launch(void* const* d_in, const int* in_sizes, int n_in,
                              void* d_out, int out_size, void* d_ws, size_t ws_size,
                              hipStream_t stream) {
    const void* pos  = d_in[0];
    const int*  z    = (const int*)d_in[1];
    // d_in[2] = batch (implicit: graph = i >> 7)
    const void* emb  = d_in[3];
    const void* mw1  = d_in[4];
    const void* mb1  = d_in[5];
    const void* mw2  = d_in[6];
    const void* mb2  = d_in[7];
    const void* l1w  = d_in[8];
    const void* l1b  = d_in[9];
    const void* l2w  = d_in[10];
    const void* l2b  = d_in[11];
    const void* ow1  = d_in[12];
    const void* ob1  = d_in[13];
    const void* ow2  = d_in[14];
    const void* ob2  = d_in[15];

    char* ws = (char*)d_ws;
    const size_t KB = 1024, MB = 1048576;
    int*   w_flag  = (int*)  (ws);
    float* c_pos   = (float*)(ws + 4   * KB);
    float* c_emb   = (float*)(ws + 112 * KB);
    float* c_mb1   = (float*)(ws + 168 * KB);
    float* c_mb2   = (float*)(ws + 176 * KB);
    float* c_l1b   = (float*)(ws + 184 * KB);
    float* c_l2b   = (float*)(ws + 192 * KB);
    float* c_ow1   = (float*)(ws + 200 * KB);
    float* c_ob1   = (float*)(ws + 236 * KB);
    float* c_ow2   = (float*)(ws + 240 * KB);
    float* c_ob2   = (float*)(ws + 244 * KB);
    float* w_gsum  = (float*)(ws + 248 * KB);
    u16*   c_l1wt  = (u16*)  (ws + 256 * KB);   // 192 KB
    u16*   c_l2wt  = (u16*)  (ws + 448 * KB);   // 192 KB
    u16*   c_mw2t  = (u16*)  (ws + 640 * KB);   // 192 KB
    u16*   c_mw1t  = (u16*)  (ws + 832 * KB);   // 96 KB
    int*   rev_cnt = (int*)  (ws + 2  * MB);    // 32 KB
    int2*  rev_si  = (int2*) (ws + 3  * MB);    // 8 MB
    float* w_h     = (float*)(ws + 11 * MB);    // 4 MB
    u16*   w_xjb   = (u16*)  (ws + 15 * MB);    // 2 MB
    float* w_agg   = (float*)(ws + 17 * MB);    // 4 MB
    u32*   w_pk    = (u32*)  (ws + 21 * MB);    // 6 MB

    probe_kernel<<<1, 256, 0, stream>>>((const u16*)emb, w_flag, rev_cnt, w_gsum);

    IngestDesc dsc;
    const void* srcs[NARR] = {pos, emb, mb1, mb2, l1b, l2b, ow1, ob1, ow2, ob2};
    void* dsts[NARR] = {c_pos, c_emb, c_mb1, c_mb2, c_l1b, c_l2b, c_ow1, c_ob1,
                        c_ow2, c_ob2};
    int ns_[NARR] = {24576, 12800, 768, 768, 768, 768, 8192, 64, 64, 1};
    int total = 0;
    for (int a = 0; a < NARR; ++a) {
        dsc.src[a] = srcs[a]; dsc.dst[a] = dsts[a]; dsc.n[a] = ns_[a];
        total += ns_[a];
    }
    ingest_kernel<<<(total + 255) / 256, 256, 0, stream>>>(dsc, w_flag, total);
    prep_weights<<<1344, 256, 0, stream>>>(l1w, l2w, mw2, mw1,
                                           c_l1wt, c_l2wt, c_mw2t, c_mw1t, w_flag);

    build_graph_kernel<<<NATOMS / 4, 256, 0, stream>>>(c_pos, rev_cnt, rev_si);
    vtab_kernel<<<LAYERS * NTAB / 128, 256, 0, stream>>>(
        c_mw1t, c_mw2t, c_mb1, c_mb2, w_pk);

    gemm0_kernel<<<NATOMS / 16, 256, 0, stream>>>(z, c_emb, c_l1wt, c_l1b, w_xjb);

    for (int l = 0; l < LAYERS; ++l) {
        agg_kernel<<<NATOMS / 4, 256, 0, stream>>>(
            rev_cnt, rev_si, w_pk + (size_t)l * NTAB * 64, w_xjb, w_agg);
        const u16* B2 = c_l2wt + (size_t)l * 16384;
        const float* b2 = c_l2b + (size_t)l * 128;
        const u16* B1n = c_l1wt + (size_t)(l + 1) * 16384;
        const float* b1n = c_l1b + (size_t)(l + 1) * 128;
        if (l == 0)
            layer_tail_kernel<1, 0><<<NATOMS / 16, 256, 0, stream>>>(
                w_agg, w_h, z, c_emb, B2, b2, B1n, b1n, w_xjb);
        else if (l < LAYERS - 1)
            layer_tail_kernel<0, 0><<<NATOMS / 16, 256, 0, stream>>>(
                w_agg, w_h, z, c_emb, B2, b2, B1n, b1n, w_xjb);
        else
            layer_tail_kernel<0, 1><<<NATOMS / 16, 256, 0, stream>>>(
                w_agg, w_h, z, c_emb, B2, b2, nullptr, nullptr, nullptr);
    }

    head_kernel<<<NATOMS / 16, 256, 0, stream>>>(w_h, c_ow1, c_ob1, c_ow2, c_ob2,
                                                 w_gsum);
    finalize_kernel<<<1, GRAPHS, 0, stream>>>(w_gsum, (void*)d_out, w_flag);
}

// Round 18
// 281.319 us; speedup vs baseline: 1.0570x; 1.0225x over previous
//
#include <hip/hip_runtime.h>
#include <math.h>

typedef unsigned short u16;
typedef unsigned int   u32;
typedef unsigned long long u64;

#define NATOMS 8192
#define GRAPHS 64
#define APG    128
#define KNN    32
#define NGAUSS 50
#define HID    128
#define LAYERS 6
#define NTAB   4096
#define SA     136   // u16 stride, 272B rows (16B-aligned, 4-bank row shift)
#define SW1    72    // u16 stride for staged mw1 rows
#define SH     132   // f32 stride, 528B rows (16B-aligned)

typedef __attribute__((ext_vector_type(8))) short bf16x8;
typedef __attribute__((ext_vector_type(4))) float f32x4;

__device__ __forceinline__ float bf2f(u16 v) {
    return __uint_as_float(((u32)v) << 16);
}
__device__ __forceinline__ u16 f2bf(float f) {
    u32 u = __float_as_uint(f);
    u32 lsb = (u >> 16) & 1u;
    u += 0x7fffu + lsb;
    return (u16)(u >> 16);
}
__device__ __forceinline__ u32 pkbf(float lo, float hi) {
#if __has_builtin(__builtin_amdgcn_cvt_pk_bf16_f32)
    auto r = __builtin_amdgcn_cvt_pk_bf16_f32(lo, hi);
    u32 u; __builtin_memcpy(&u, &r, 4); return u;
#else
    return (u32)f2bf(lo) | ((u32)f2bf(hi) << 16);
#endif
}
__device__ __forceinline__ float silu_f(float x) {
    return x * __builtin_amdgcn_rcpf(1.0f + __expf(-x));
}
__device__ __forceinline__ bf16x8 ldfrag(const u16* p) {
    return *(const bf16x8*)__builtin_assume_aligned(p, 16);
}
__device__ __forceinline__ u64 shfl_xor_u64(u64 v, int mask) {
    u32 lo = (u32)v, hi = (u32)(v >> 32);
    lo = (u32)__shfl_xor((int)lo, mask, 64);
    hi = (u32)__shfl_xor((int)hi, mask, 64);
    return ((u64)hi << 32) | lo;
}
union U8 { bf16x8 v; u32 w[4]; };

// ---------------------------------------------------------------------------
// K0: dtype probe + zero rev_cnt/gsum (folds 2 memset dispatches).
// ---------------------------------------------------------------------------
__global__ void probe_kernel(const u16* __restrict__ raw, int* __restrict__ flag,
                             int* __restrict__ rev_cnt, float* __restrict__ gsum) {
    __shared__ int s;
    int t = threadIdx.x;
    if (t == 0) s = 0;
    __syncthreads();
    float x = bf2f(raw[2 * t]);
    if (!(fabsf(x) < 1000.0f)) atomicOr(&s, 1);
    for (int i = t; i < NATOMS; i += 256) rev_cnt[i] = 0;
    if (t < GRAPHS) gsum[t] = 0.0f;
    __syncthreads();
    if (t == 0) *flag = s;
}

// ---------------------------------------------------------------------------
// K0b: ingest fp32-canonical copies (small arrays only).
// ---------------------------------------------------------------------------
#define NARR 10
struct IngestDesc {
    const void* src[NARR];
    void*       dst[NARR];
    int         n[NARR];
};

__global__ void ingest_kernel(IngestDesc d, const int* __restrict__ flag, int total) {
    int gid = blockIdx.x * blockDim.x + threadIdx.x;
    if (gid >= total) return;
    int a = 0, off = gid;
    while (off >= d.n[a]) { off -= d.n[a]; ++a; }
    bool f32in = (*flag != 0);
    float v = f32in ? ((const float*)d.src[a])[off]
                    : bf2f(((const u16*)d.src[a])[off]);
    ((float*)d.dst[a])[off] = v;
}

// ---------------------------------------------------------------------------
// K0c: weight prep — transpose l1w/l2w/mw2 to [n][k] bf16; mw1 -> [n][64]
// (k>=50 zero-padded). All are MFMA B-operands.
// ---------------------------------------------------------------------------
__global__ void prep_weights(const void* __restrict__ l1w, const void* __restrict__ l2w,
                             const void* __restrict__ mw2, const void* __restrict__ mw1,
                             u16* __restrict__ l1wt, u16* __restrict__ l2wt,
                             u16* __restrict__ mw2t, u16* __restrict__ mw1t,
                             const int* __restrict__ flag) {
    int gid = blockIdx.x * blockDim.x + threadIdx.x;
    bool f32in = (*flag != 0);
    if (gid < 3 * 98304) {
        int seg = gid / 98304;
        int t = gid % 98304;
        int l = t >> 14;
        int n = (t >> 7) & 127;
        int k = t & 127;
        const void* src = (seg == 0) ? l1w : ((seg == 1) ? l2w : mw2);
        u16* dst = (seg == 0) ? l1wt : ((seg == 1) ? l2wt : mw2t);
        int si = l * 16384 + k * 128 + n;
        float v = f32in ? ((const float*)src)[si] : bf2f(((const u16*)src)[si]);
        dst[t] = f2bf(v);
    } else {
        int t = gid - 3 * 98304;
        if (t < 49152) {
            int l = t >> 13;
            int n = (t >> 6) & 127;
            int k = t & 63;
            float v = 0.0f;
            if (k < 50) {
                int si = l * 6400 + k * 128 + n;
                v = f32in ? ((const float*)mw1)[si] : bf2f(((const u16*)mw1)[si]);
            }
            mw1t[t] = f2bf(v);
        }
    }
}

// ---------------------------------------------------------------------------
// K1: graph build + edge prep. One WAVE per center; full bitonic sort of 128
// (d2,j) u64 keys (verified R10-R17). Valid edges -> receiver lists with
// (src atom, NEAREST table row index).
// ---------------------------------------------------------------------------
__launch_bounds__(256)
__global__ void build_graph_kernel(const float* __restrict__ pos,
                                   int* __restrict__ rev_cnt,
                                   int2* __restrict__ rev_si) {
    int wv = threadIdx.x >> 6, lane = threadIdx.x & 63;
    int t = blockIdx.x * 4 + wv;
    int tl = t & 127;
    int base = t & ~127;
    float cx = pos[t * 3 + 0];
    float cy = pos[t * 3 + 1];
    float cz = pos[t * 3 + 2];
    u64 key[2];
#pragma unroll
    for (int c = 0; c < 2; ++c) {
        int j = lane + c * 64;
        float jx = pos[(base + j) * 3 + 0];
        float jy = pos[(base + j) * 3 + 1];
        float jz = pos[(base + j) * 3 + 2];
        float dx = __fsub_rn(cx, jx);
        float dy = __fsub_rn(cy, jy);
        float dz = __fsub_rn(cz, jz);
        float d2 = __fadd_rn(__fadd_rn(__fmul_rn(dx, dx), __fmul_rn(dy, dy)),
                             __fmul_rn(dz, dz));
        bool valid = (j != tl) && (d2 < 100.0f);
        key[c] = valid ? ((((u64)__float_as_uint(d2)) << 32) | (u32)j) : ~0ULL;
    }
#pragma unroll
    for (int k = 2; k <= 128; k <<= 1) {
#pragma unroll
        for (int j = k >> 1; j > 0; j >>= 1) {
            if (j == 64) {
                u64 lo = key[0] < key[1] ? key[0] : key[1];
                u64 hi = key[0] < key[1] ? key[1] : key[0];
                key[0] = lo; key[1] = hi;
            } else {
#pragma unroll
                for (int r = 0; r < 2; ++r) {
                    u64 o = shfl_xor_u64(key[r], j);
                    u32 ii = (u32)(r * 64 + lane);
                    bool dir = ((ii & (u32)k) == 0);
                    bool lower = ((ii & (u32)j) == 0);
                    bool keep_min = (dir == lower);
                    bool less = key[r] < o;
                    key[r] = (less == keep_min) ? key[r] : o;
                }
            }
        }
    }
    if (lane < KNN) {
        u64 m = key[0];
        if (m != ~0ULL) {
            float d2 = __uint_as_float((u32)(m >> 32));
            float d = __fsqrt_rn(d2);
            if (d < 10.0f) {
                float u = d * ((float)(NTAB - 1) / 10.0f);
                int i0 = (int)(u + 0.5f);          // nearest
                if (i0 > NTAB - 1) i0 = NTAB - 1;
                int jn = base + (int)(m & 0xffffffffu);
                int p = atomicAdd(&rev_cnt[jn], 1);
                rev_si[(size_t)jn * 128 + p] = make_int2(t, i0);
            }
        }
    }
}

// ---------------------------------------------------------------------------
// K4a: filter tables via MFMA. R18: w1/w2 staged in LDS (padded strides,
// 4-bank row shift) — removes global-load latency from the MFMA chain;
// blocks are grid-limited so the extra LDS is free. Math identical to R17.
// ---------------------------------------------------------------------------
__launch_bounds__(256)
__global__ void vtab_kernel(const u16* __restrict__ mw1t,   // [6][128][64]
                            const u16* __restrict__ mw2t,   // [6][128][128]
                            const float* __restrict__ b1,   // [6][128]
                            const float* __restrict__ b2,   // [6][128]
                            u32* __restrict__ pk) {         // [6][NTAB][64]
    __shared__ u16 s_t1[128 * SA];     // 34.8 KB
    __shared__ u16 s_w1[128 * SW1];    // 18.4 KB
    __shared__ u16 s_w2[128 * SA];     // 34.8 KB
    int tid = threadIdx.x;
    int l = blockIdx.x / (NTAB / 128);
    int rbase = (blockIdx.x % (NTAB / 128)) * 128;
    {
        const uint4* g1 = (const uint4*)(mw1t + (size_t)l * 8192);
#pragma unroll
        for (int p = 0; p < 4; ++p) {
            int q = tid + p * 256;                 // 1024 chunks of 8 u16
            int row = q >> 3, c8 = (q & 7) * 8;
            *(uint4*)&s_w1[row * SW1 + c8] = g1[q];
        }
        const uint4* g2 = (const uint4*)(mw2t + (size_t)l * 16384);
#pragma unroll
        for (int p = 0; p < 8; ++p) {
            int q = tid + p * 256;                 // 2048 chunks
            int row = q >> 4, c8 = (q & 15) * 8;
            *(uint4*)&s_w2[row * SA + c8] = g2[q];
        }
    }
    __syncthreads();

    int wv = tid >> 6, lane = tid & 63;
    int quad = lane >> 4, lr = lane & 15;
    int m0 = wv * 32;

    // Phase A: t1 = silu(rbf @ mw1 + b1), rbf per-lane in registers
    {
        const float wgi = 49.0f / 10.0f;
        const float dstep = 10.0f / (float)(NTAB - 1);
        U8 afr[2][2];
#pragma unroll
        for (int mt = 0; mt < 2; ++mt) {
            float d = (float)(rbase + m0 + mt * 16 + lr) * dstep;
            float u = d * wgi;
#pragma unroll
            for (int kki = 0; kki < 2; ++kki) {
                float t0 = u - (float)(quad * 8) - (float)(kki * 32);
                float vj[8];
#pragma unroll
                for (int j = 0; j < 8; ++j) {
                    float tt = t0 - (float)j;
                    float e = __expf(-0.5f * tt * tt);
                    if (kki == 1 && (quad * 8 + j) >= 18) e = 0.0f;  // k>=50 pad
                    vj[j] = e;
                }
#pragma unroll
                for (int p = 0; p < 4; ++p)
                    afr[mt][kki].w[p] = pkbf(vj[2 * p], vj[2 * p + 1]);
            }
        }
        f32x4 accA[2][8];
#pragma unroll
        for (int mt = 0; mt < 2; ++mt)
#pragma unroll
            for (int nt = 0; nt < 8; ++nt) accA[mt][nt] = (f32x4){0.f, 0.f, 0.f, 0.f};
#pragma unroll
        for (int kki = 0; kki < 2; ++kki) {
#pragma unroll
            for (int nt = 0; nt < 8; ++nt) {
                bf16x8 b = ldfrag(&s_w1[(nt * 16 + lr) * SW1 + kki * 32 + quad * 8]);
                accA[0][nt] = __builtin_amdgcn_mfma_f32_16x16x32_bf16(afr[0][kki].v, b, accA[0][nt], 0, 0, 0);
                accA[1][nt] = __builtin_amdgcn_mfma_f32_16x16x32_bf16(afr[1][kki].v, b, accA[1][nt], 0, 0, 0);
            }
        }
#pragma unroll
        for (int mt = 0; mt < 2; ++mt) {
            int r0 = m0 + mt * 16 + quad * 4;
            u16* tp0 = &s_t1[r0 * SA + lr];
#pragma unroll
            for (int nt = 0; nt < 8; ++nt) {
                int col = nt * 16;
                float bb = b1[l * 128 + col + lr];
                u32 p01 = pkbf(silu_f(accA[mt][nt][0] + bb),
                               silu_f(accA[mt][nt][1] + bb));
                u32 p23 = pkbf(silu_f(accA[mt][nt][2] + bb),
                               silu_f(accA[mt][nt][3] + bb));
                u16* tp = tp0 + col;
                tp[0]      = (u16)p01;
                tp[SA]     = (u16)(p01 >> 16);
                tp[2 * SA] = (u16)p23;
                tp[3 * SA] = (u16)(p23 >> 16);
            }
        }
    }
    // no barrier: Phase B reads only this wave's own 32 t1 rows

    // Phase B: V = (t1 @ mw2 + b2) * cv(d), pair-packed bf16 out
    {
        f32x4 accB[2][8];
#pragma unroll
        for (int mt = 0; mt < 2; ++mt)
#pragma unroll
            for (int nt = 0; nt < 8; ++nt) accB[mt][nt] = (f32x4){0.f, 0.f, 0.f, 0.f};
#pragma unroll
        for (int kk = 0; kk < 128; kk += 32) {
            bf16x8 a0 = ldfrag(&s_t1[(m0 + lr)      * SA + kk + quad * 8]);
            bf16x8 a1 = ldfrag(&s_t1[(m0 + 16 + lr) * SA + kk + quad * 8]);
#pragma unroll
            for (int nt = 0; nt < 8; ++nt) {
                bf16x8 b = ldfrag(&s_w2[(nt * 16 + lr) * SA + kk + quad * 8]);
                accB[0][nt] = __builtin_amdgcn_mfma_f32_16x16x32_bf16(a0, b, accB[0][nt], 0, 0, 0);
                accB[1][nt] = __builtin_amdgcn_mfma_f32_16x16x32_bf16(a1, b, accB[1][nt], 0, 0, 0);
            }
        }
        const float dstep = 10.0f / (float)(NTAB - 1);
#pragma unroll
        for (int mt = 0; mt < 2; ++mt) {
            int r0 = m0 + mt * 16 + quad * 4;
            float cv[4];
#pragma unroll
            for (int r = 0; r < 4; ++r) {
                float d = (float)(rbase + r0 + r) * dstep;
                cv[r] = 0.5f * (cosf(d * 3.14159265f / 10.0f) + 1.0f);
            }
#pragma unroll
            for (int nt = 0; nt < 8; ++nt) {
                int col = nt * 16 + lr;
                float bb = b2[l * 128 + col];
#pragma unroll
                for (int r = 0; r < 4; ++r) {
                    float val = (accB[mt][nt][r] + bb) * cv[r];
                    float oth = __shfl_xor(val, 1, 64);
                    if ((lr & 1) == 0) {
                        int row = rbase + r0 + r;
                        pk[((size_t)l * NTAB + row) * 64 + (col >> 1)] =
                            pkbf(val, oth);
                    }
                }
            }
        }
    }
}

// ---------------------------------------------------------------------------
// K3a: initial gemm0 — xj(0) = emb[z] @ l1w(0) + b1(0), bf16 out.
// ---------------------------------------------------------------------------
__launch_bounds__(256)
__global__ void gemm0_kernel(const int* __restrict__ z,
                             const float* __restrict__ emb,
                             const u16* __restrict__ Bt,
                             const float* __restrict__ bias,
                             u16* __restrict__ xjb) {
    __shared__ u16 s_a[16 * SA];
    __shared__ float s_bias[128];
    int tid = threadIdx.x;
    int row0 = blockIdx.x * 16;
#pragma unroll
    for (int p = 0; p < 2; ++p) {
        int q = tid + p * 256;
        int r = q >> 5, c4 = (q & 31) * 4;
        const float* src = emb + (size_t)z[row0 + r] * 128;
        float4 v = *(const float4*)(src + c4);
        u32* d = (u32*)&s_a[r * SA + c4];
        d[0] = pkbf(v.x, v.y); d[1] = pkbf(v.z, v.w);
    }
    if (tid < 128) s_bias[tid] = bias[tid];
    __syncthreads();
    int wv = tid >> 6, lane = tid & 63;
    int quad = lane >> 4, lr = lane & 15;
    int n0 = wv * 32;
    f32x4 acc[2];
#pragma unroll
    for (int nt = 0; nt < 2; ++nt) acc[nt] = (f32x4){0.f, 0.f, 0.f, 0.f};
#pragma unroll
    for (int kk = 0; kk < 128; kk += 32) {
        bf16x8 a = ldfrag(&s_a[lr * SA + kk + quad * 8]);
#pragma unroll
        for (int nt = 0; nt < 2; ++nt) {
            bf16x8 b = ldfrag(Bt + (n0 + nt * 16 + lr) * 128 + kk + quad * 8);
            acc[nt] = __builtin_amdgcn_mfma_f32_16x16x32_bf16(a, b, acc[nt], 0, 0, 0);
        }
    }
#pragma unroll
    for (int nt = 0; nt < 2; ++nt)
#pragma unroll
        for (int r = 0; r < 4; ++r) {
            int col = n0 + nt * 16 + lr;
            xjb[(size_t)(row0 + quad * 4 + r) * 128 + col] =
                f2bf(acc[nt][r] + s_bias[col]);
        }
}

// ---------------------------------------------------------------------------
// K4c: aggregate (R15-proven form). One wave per receiver; NEAREST table
// (4B/lane/edge) + bf16 xj (4B); fp32 accumulate; 8-wide unroll.
// ---------------------------------------------------------------------------
__launch_bounds__(256, 4)
__global__ void agg_kernel(const int* __restrict__ rev_cnt,
                           const int2* __restrict__ rev_si,
                           const u32* __restrict__ pk,
                           const u16* __restrict__ xjb,
                           float* __restrict__ agg) {
    int j = blockIdx.x * 4 + (threadIdx.x >> 6);
    int lane = threadIdx.x & 63;
    int deg = rev_cnt[j];
    const int2* si = rev_si + (size_t)j * 128;
    int c2 = lane * 2;
    float a0 = 0.f, a1 = 0.f, b0 = 0.f, b1 = 0.f;
    float c0 = 0.f, c1 = 0.f, d0 = 0.f, d1 = 0.f;
    int it = 0;
    for (; it + 8 <= deg; it += 8) {
        u32 t[8], x[8];
#pragma unroll
        for (int q = 0; q < 8; ++q) {
            int2 s = si[it + q];
            t[q] = pk[(size_t)s.y * 64 + lane];
            x[q] = *(const u32*)(xjb + (size_t)s.x * 128 + c2);
        }
#pragma unroll
        for (int q = 0; q < 8; ++q) {
            float v0 = bf2f((u16)t[q]) * bf2f((u16)x[q]);
            float v1 = bf2f((u16)(t[q] >> 16)) * bf2f((u16)(x[q] >> 16));
            switch (q & 3) {
                case 0: a0 += v0; a1 += v1; break;
                case 1: b0 += v0; b1 += v1; break;
                case 2: c0 += v0; c1 += v1; break;
                default: d0 += v0; d1 += v1; break;
            }
        }
    }
    for (; it + 4 <= deg; it += 4) {
        u32 t[4], x[4];
#pragma unroll
        for (int q = 0; q < 4; ++q) {
            int2 s = si[it + q];
            t[q] = pk[(size_t)s.y * 64 + lane];
            x[q] = *(const u32*)(xjb + (size_t)s.x * 128 + c2);
        }
#pragma unroll
        for (int q = 0; q < 4; ++q) {
            float v0 = bf2f((u16)t[q]) * bf2f((u16)x[q]);
            float v1 = bf2f((u16)(t[q] >> 16)) * bf2f((u16)(x[q] >> 16));
            if (q == 0) { a0 += v0; a1 += v1; }
            else if (q == 1) { b0 += v0; b1 += v1; }
            else if (q == 2) { c0 += v0; c1 += v1; }
            else { d0 += v0; d1 += v1; }
        }
    }
    for (; it < deg; ++it) {
        int2 s = si[it];
        u32 t = pk[(size_t)s.y * 64 + lane];
        u32 x = *(const u32*)(xjb + (size_t)s.x * 128 + c2);
        a0 += bf2f((u16)t) * bf2f((u16)x);
        a1 += bf2f((u16)(t >> 16)) * bf2f((u16)(x >> 16));
    }
    float2 r;
    r.x = (a0 + b0) + (c0 + d0);
    r.y = (a1 + b1) + (c1 + d1);
    *(float2*)(agg + (size_t)j * 128 + c2) = r;
}

// ---------------------------------------------------------------------------
// K3b: layer tail — h += silu(agg @ l2w + b2) [hi/lo split A]; then (unless
// LAST) xj(l+1) = h_new @ l1w(l+1) + b1(l+1). EMB=1: h_old = emb[z].
// ---------------------------------------------------------------------------
template <int EMB, int LAST>
__launch_bounds__(256)
__global__ void layer_tail_kernel(const float* __restrict__ agg,
                                  float* __restrict__ h,
                                  const int* __restrict__ z,
                                  const float* __restrict__ emb,
                                  const u16* __restrict__ B2t,
                                  const float* __restrict__ b2,
                                  const u16* __restrict__ B1n,
                                  const float* __restrict__ b1n,
                                  u16* __restrict__ xjb) {
    __shared__ u16 s_ahi[16 * SA];
    __shared__ u16 s_alo[16 * SA];
    __shared__ float s_h[16 * SH];
    __shared__ float s_b2[128], s_b1[128];
    int tid = threadIdx.x;
    int row0 = blockIdx.x * 16;
#pragma unroll
    for (int p = 0; p < 2; ++p) {
        int q = tid + p * 256;
        int r = q >> 5, c4 = (q & 31) * 4;
        float4 v = *(const float4*)(agg + (size_t)(row0 + r) * 128 + c4);
        u32 h0 = pkbf(v.x, v.y), h1 = pkbf(v.z, v.w);
        u32* hd = (u32*)&s_ahi[r * SA + c4];
        hd[0] = h0; hd[1] = h1;
        u32 l0 = pkbf(v.x - bf2f((u16)h0), v.y - bf2f((u16)(h0 >> 16)));
        u32 l1 = pkbf(v.z - bf2f((u16)h1), v.w - bf2f((u16)(h1 >> 16)));
        u32* ld = (u32*)&s_alo[r * SA + c4];
        ld[0] = l0; ld[1] = l1;
    }
    if (tid < 128) {
        s_b2[tid] = b2[tid];
        if (!LAST) s_b1[tid] = b1n[tid];
    }
    __syncthreads();

    int wv = tid >> 6, lane = tid & 63;
    int quad = lane >> 4, lr = lane & 15;
    int n0 = wv * 32;

    f32x4 acc[2];
#pragma unroll
    for (int nt = 0; nt < 2; ++nt) acc[nt] = (f32x4){0.f, 0.f, 0.f, 0.f};
#pragma unroll
    for (int kk = 0; kk < 128; kk += 32) {
        bf16x8 ah = ldfrag(&s_ahi[lr * SA + kk + quad * 8]);
        bf16x8 al = ldfrag(&s_alo[lr * SA + kk + quad * 8]);
#pragma unroll
        for (int nt = 0; nt < 2; ++nt) {
            bf16x8 b = ldfrag(B2t + (n0 + nt * 16 + lr) * 128 + kk + quad * 8);
            acc[nt] = __builtin_amdgcn_mfma_f32_16x16x32_bf16(ah, b, acc[nt], 0, 0, 0);
            acc[nt] = __builtin_amdgcn_mfma_f32_16x16x32_bf16(al, b, acc[nt], 0, 0, 0);
        }
    }
#pragma unroll
    for (int nt = 0; nt < 2; ++nt)
#pragma unroll
        for (int r = 0; r < 4; ++r) {
            int row = quad * 4 + r;
            int col = n0 + nt * 16 + lr;
            size_t off = (size_t)(row0 + row) * 128 + col;
            float hold = EMB ? emb[(size_t)z[row0 + row] * 128 + col] : h[off];
            float hn = hold + silu_f(acc[nt][r] + s_b2[col]);
            h[off] = hn;
            s_h[row * SH + col] = hn;
        }
    if (!LAST) {
        __syncthreads();
        f32x4 ac2[2];
#pragma unroll
        for (int nt = 0; nt < 2; ++nt) ac2[nt] = (f32x4){0.f, 0.f, 0.f, 0.f};
#pragma unroll
        for (int kk = 0; kk < 128; kk += 32) {
            const float* ap = &s_h[lr * SH + kk + quad * 8];
            float4 v0 = *(const float4*)ap;
            float4 v1 = *(const float4*)(ap + 4);
            U8 a;
            a.w[0] = pkbf(v0.x, v0.y); a.w[1] = pkbf(v0.z, v0.w);
            a.w[2] = pkbf(v1.x, v1.y); a.w[3] = pkbf(v1.z, v1.w);
#pragma unroll
            for (int nt = 0; nt < 2; ++nt) {
                bf16x8 b = ldfrag(B1n + (n0 + nt * 16 + lr) * 128 + kk + quad * 8);
                ac2[nt] = __builtin_amdgcn_mfma_f32_16x16x32_bf16(a.v, b, ac2[nt], 0, 0, 0);
            }
        }
#pragma unroll
        for (int nt = 0; nt < 2; ++nt)
#pragma unroll
            for (int r = 0; r < 4; ++r) {
                int col = n0 + nt * 16 + lr;
                xjb[(size_t)(row0 + quad * 4 + r) * 128 + col] =
                    f2bf(ac2[nt][r] + s_b1[col]);
            }
    }
}

// ---------------------------------------------------------------------------
// K6: output head — 16 atoms/block, LDS-tiled, one atomic per block.
// ---------------------------------------------------------------------------
__launch_bounds__(256)
__global__ void head_kernel(const float* __restrict__ h,
                            const float* __restrict__ ow1,
                            const float* __restrict__ ob1,
                            const float* __restrict__ ow2,
                            const float* __restrict__ ob2,
                            float* __restrict__ gsum) {
    __shared__ __align__(16) float s_w[128 * 64];
    __shared__ __align__(16) float s_h[16 * 132];
    __shared__ float s_sum;
    int tid = threadIdx.x;
    int a0 = blockIdx.x * 16;
    if (tid == 0) s_sum = 0.0f;
    {
        const float4* src = (const float4*)ow1;
        float4* dst = (float4*)s_w;
#pragma unroll
        for (int p = 0; p < 8; ++p) dst[tid + p * 256] = src[tid + p * 256];
    }
    {
        const float4* src = (const float4*)(h + (size_t)a0 * 128);
#pragma unroll
        for (int p = 0; p < 2; ++p) {
            int q = tid + p * 256;
            int r = q >> 5, c4 = (q & 31) * 4;
            *(float4*)&s_h[r * 132 + c4] = src[q];
        }
    }
    __syncthreads();
    int atom = tid >> 4, cg = tid & 15;
    const float* hr = &s_h[atom * 132];
    const float4* w4 = (const float4*)s_w;
    float4 acc = {0.f, 0.f, 0.f, 0.f};
#pragma unroll 8
    for (int f = 0; f < 128; ++f) {
        float hv = hr[f];
        float4 w = w4[f * 16 + cg];
        acc.x += hv * w.x; acc.y += hv * w.y;
        acc.z += hv * w.z; acc.w += hv * w.w;
    }
    int c0 = cg * 4;
    float v = silu_f(acc.x + ob1[c0 + 0]) * ow2[c0 + 0]
            + silu_f(acc.y + ob1[c0 + 1]) * ow2[c0 + 1]
            + silu_f(acc.z + ob1[c0 + 2]) * ow2[c0 + 2]
            + silu_f(acc.w + ob1[c0 + 3]) * ow2[c0 + 3];
    v += __shfl_xor(v, 1, 64);
    v += __shfl_xor(v, 2, 64);
    v += __shfl_xor(v, 4, 64);
    v += __shfl_xor(v, 8, 64);
    if ((tid & 15) == 0) atomicAdd(&s_sum, v + ob2[0]);
    __syncthreads();
    if (tid == 0) atomicAdd(&gsum[a0 >> 7], s_sum);
}

__global__ void finalize_kernel(const float* __restrict__ gsum, void* __restrict__ out,
                                const int* __restrict__ flag) {
    int t = threadIdx.x;
    if (*flag) ((float*)out)[t] = gsum[t];
    else       ((u16*)out)[t]   = f2bf(gsum[t]);
}

// ---------------------------------------------------------------------------
extern "C" void kernel_launch(void* const* d_in, const int* in_sizes, int n_in,
                              void* d_out, int out_size, void* d_ws, size_t ws_size,
                              hipStream_t stream) {
    const void* pos  = d_in[0];
    const int*  z    = (const int*)d_in[1];
    // d_in[2] = batch (implicit: graph = i >> 7)
    const void* emb  = d_in[3];
    const void* mw1  = d_in[4];
    const void* mb1  = d_in[5];
    const void* mw2  = d_in[6];
    const void* mb2  = d_in[7];
    const void* l1w  = d_in[8];
    const void* l1b  = d_in[9];
    const void* l2w  = d_in[10];
    const void* l2b  = d_in[11];
    const void* ow1  = d_in[12];
    const void* ob1  = d_in[13];
    const void* ow2  = d_in[14];
    const void* ob2  = d_in[15];

    char* ws = (char*)d_ws;
    const size_t KB = 1024, MB = 1048576;
    int*   w_flag  = (int*)  (ws);
    float* c_pos   = (float*)(ws + 4   * KB);
    float* c_emb   = (float*)(ws + 112 * KB);
    float* c_mb1   = (float*)(ws + 168 * KB);
    float* c_mb2   = (float*)(ws + 176 * KB);
    float* c_l1b   = (float*)(ws + 184 * KB);
    float* c_l2b   = (float*)(ws + 192 * KB);
    float* c_ow1   = (float*)(ws + 200 * KB);
    float* c_ob1   = (float*)(ws + 236 * KB);
    float* c_ow2   = (float*)(ws + 240 * KB);
    float* c_ob2   = (float*)(ws + 244 * KB);
    float* w_gsum  = (float*)(ws + 248 * KB);
    u16*   c_l1wt  = (u16*)  (ws + 256 * KB);   // 192 KB
    u16*   c_l2wt  = (u16*)  (ws + 448 * KB);   // 192 KB
    u16*   c_mw2t  = (u16*)  (ws + 640 * KB);   // 192 KB
    u16*   c_mw1t  = (u16*)  (ws + 832 * KB);   // 96 KB
    int*   rev_cnt = (int*)  (ws + 2  * MB);    // 32 KB
    int2*  rev_si  = (int2*) (ws + 3  * MB);    // 8 MB
    float* w_h     = (float*)(ws + 11 * MB);    // 4 MB
    u16*   w_xjb   = (u16*)  (ws + 15 * MB);    // 2 MB
    float* w_agg   = (float*)(ws + 17 * MB);    // 4 MB
    u32*   w_pk    = (u32*)  (ws + 21 * MB);    // 6 MB

    probe_kernel<<<1, 256, 0, stream>>>((const u16*)emb, w_flag, rev_cnt, w_gsum);

    IngestDesc dsc;
    const void* srcs[NARR] = {pos, emb, mb1, mb2, l1b, l2b, ow1, ob1, ow2, ob2};
    void* dsts[NARR] = {c_pos, c_emb, c_mb1, c_mb2, c_l1b, c_l2b, c_ow1, c_ob1,
                        c_ow2, c_ob2};
    int ns_[NARR] = {24576, 12800, 768, 768, 768, 768, 8192, 64, 64, 1};
    int total = 0;
    for (int a = 0; a < NARR; ++a) {
        dsc.src[a] = srcs[a]; dsc.dst[a] = dsts[a]; dsc.n[a] = ns_[a];
        total += ns_[a];
    }
    ingest_kernel<<<(total + 255) / 256, 256, 0, stream>>>(dsc, w_flag, total);
    prep_weights<<<1344, 256, 0, stream>>>(l1w, l2w, mw2, mw1,
                                           c_l1wt, c_l2wt, c_mw2t, c_mw1t, w_flag);

    build_graph_kernel<<<NATOMS / 4, 256, 0, stream>>>(c_pos, rev_cnt, rev_si);
    vtab_kernel<<<LAYERS * NTAB / 128, 256, 0, stream>>>(
        c_mw1t, c_mw2t, c_mb1, c_mb2, w_pk);

    gemm0_kernel<<<NATOMS / 16, 256, 0, stream>>>(z, c_emb, c_l1wt, c_l1b, w_xjb);

    for (int l = 0; l < LAYERS; ++l) {
        agg_kernel<<<NATOMS / 4, 256, 0, stream>>>(
            rev_cnt, rev_si, w_pk + (size_t)l * NTAB * 64, w_xjb, w_agg);
        const u16* B2 = c_l2wt + (size_t)l * 16384;
        const float* b2 = c_l2b + (size_t)l * 128;
        const u16* B1n = c_l1wt + (size_t)(l + 1) * 16384;
        const float* b1n = c_l1b + (size_t)(l + 1) * 128;
        if (l == 0)
            layer_tail_kernel<1, 0><<<NATOMS / 16, 256, 0, stream>>>(
                w_agg, w_h, z, c_emb, B2, b2, B1n, b1n, w_xjb);
        else if (l < LAYERS - 1)
            layer_tail_kernel<0, 0><<<NATOMS / 16, 256, 0, stream>>>(
                w_agg, w_h, z, c_emb, B2, b2, B1n, b1n, w_xjb);
        else
            layer_tail_kernel<0, 1><<<NATOMS / 16, 256, 0, stream>>>(
                w_agg, w_h, z, c_emb, B2, b2, nullptr, nullptr, nullptr);
    }

    head_kernel<<<NATOMS / 16, 256, 0, stream>>>(w_h, c_ow1, c_ob1, c_ow2, c_ob2,
                                                 w_gsum);
    finalize_kernel<<<1, GRAPHS, 0, stream>>>(w_gsum, (void*)d_out, w_flag);
}